// Round 9
// baseline (453.139 us; speedup 1.0000x reference)
//
#include <hip/hip_runtime.h>
#include <hip/hip_bf16.h>

#define N_NODES 50000
#define N_EDGES 600000
#define D_IN 256
#define D 128

typedef unsigned short ushort_t;
typedef __attribute__((ext_vector_type(8))) short bf16x8;
typedef __attribute__((ext_vector_type(16))) float f32x16;

__device__ __forceinline__ float bf2f(ushort_t u) {
  union { unsigned int i; float f; } v;
  v.i = ((unsigned int)u) << 16;
  return v.f;
}
__device__ __forceinline__ ushort_t f2bf(float f) {
  union { float f; unsigned int i; } v;
  v.f = f;
  unsigned int x = v.i;
  unsigned int r = (x + 0x7FFFu + ((x >> 16) & 1u)) >> 16;  // RNE
  return (ushort_t)r;
}

// ---------------- dtype detection (insurance; expected all-fp32) ----------------
__global__ void k_detect(const void* e, const void* wn, const void* bn,
                         const void* w1, const void* b1, const void* w2,
                         const void* b2, int* flags) {
  const void* ptrs[7] = {e, wn, bn, w1, b1, w2, b2};
  const int ns[7] = {12800000, 32768, 128, 16384, 128, 16384, 128};
  __shared__ int red[256];
  int t = threadIdx.x;
  for (int a = 0; a < 7; a++) {
    int pn = ns[a] < 2048 ? ns[a] : 2048;
    const ushort_t* p = (const ushort_t*)ptrs[a];
    int cnt = 0;
    for (int i = t; i < pn; i += 256) {
      ushort_t u = p[i];
      int ex = (u >> 7) & 0xFF;
      if ((u & 0x7FFF) == 0 || (ex >= 100 && ex <= 130)) cnt++;
    }
    red[t] = cnt;
    __syncthreads();
    for (int off = 128; off > 0; off >>= 1) {
      if (t < off) red[t] += red[t + off];
      __syncthreads();
    }
    if (t == 0) flags[a] = (red[0] * 100 >= pn * 85) ? 1 : 0;
    __syncthreads();
  }
}

// Split w2 into bf16 hi/lo; canonicalize b1/b2 to fp32.
__global__ void k_split(const void* w2, const void* b1, const void* b2,
                        const int* __restrict__ flags,
                        ushort_t* __restrict__ w2H, ushort_t* __restrict__ w2L,
                        float* __restrict__ b1f, float* __restrict__ b2f) {
  int i = blockIdx.x * blockDim.x + threadIdx.x;
  if (i >= 16640) return;
  if (i < 16384) {
    int fl = flags[5];
    float v = fl ? bf2f(((const ushort_t*)w2)[i]) : ((const float*)w2)[i];
    ushort_t h = f2bf(v);
    w2H[i] = h;
    w2L[i] = f2bf(v - bf2f(h));
  } else if (i < 16512) {
    int j = i - 16384;
    b1f[j] = flags[4] ? bf2f(((const ushort_t*)b1)[j]) : ((const float*)b1)[j];
  } else {
    int j = i - 16512;
    b2f[j] = flags[6] ? bf2f(((const ushort_t*)b2)[j]) : ((const float*)b2)[j];
  }
}

// Fused first-layer weight: Wc = w1 @ Wn  ([128,256]), bc = w1 @ bn.
// t1 = (e@Wn^T + bn)@w1^T  ==  e@Wc^T + bc   (exact algebra).
__global__ __launch_bounds__(256) void k_wc(
    const void* wn, const void* w1, const void* bn, const int* __restrict__ flags,
    ushort_t* __restrict__ WcH, ushort_t* __restrict__ WcL, float* __restrict__ bc) {
  int j = blockIdx.x;   // 0..127
  int k = threadIdx.x;  // 0..255
  int flWn = flags[1], flW1 = flags[3], flBn = flags[2];
  float acc = 0.f;
  for (int m = 0; m < 128; m++) {
    float a = flW1 ? bf2f(((const ushort_t*)w1)[j * 128 + m])
                   : ((const float*)w1)[j * 128 + m];
    float b = flWn ? bf2f(((const ushort_t*)wn)[m * 256 + k])
                   : ((const float*)wn)[m * 256 + k];
    acc += a * b;
  }
  ushort_t h = f2bf(acc);
  WcH[j * 256 + k] = h;
  WcL[j * 256 + k] = f2bf(acc - bf2f(h));
  if (k == 0) {
    float s = 0.f;
    for (int m = 0; m < 128; m++) {
      float a = flW1 ? bf2f(((const ushort_t*)w1)[j * 128 + m])
                     : ((const float*)w1)[j * 128 + m];
      float b = flBn ? bf2f(((const ushort_t*)bn)[m]) : ((const float*)bn)[m];
      s += a * b;
    }
    bc[j] = s;
  }
}

// ---------------- CSR build ----------------

__global__ void k_deg(const int* __restrict__ dst, int* __restrict__ deg) {
  int e = blockIdx.x * blockDim.x + threadIdx.x;
  if (e < N_EDGES) atomicAdd(&deg[dst[e]], 1);
}

// Single-block full prefix scan over 50000 degrees (+ dinv).
__global__ __launch_bounds__(1024) void k_scan_all(
    const int* __restrict__ deg, int* __restrict__ row_start,
    float* __restrict__ dinv) {
  __shared__ int lds[1024];
  const int PT = 49;  // 1024*49 = 50176 >= 50000
  int t = threadIdx.x;
  int base = t * PT;
  int s = 0;
  for (int i = 0; i < PT; i++) {
    int idx = base + i;
    if (idx < N_NODES) s += deg[idx];
  }
  lds[t] = s;
  __syncthreads();
  for (int off = 1; off < 1024; off <<= 1) {
    int add = (t >= off) ? lds[t - off] : 0;
    __syncthreads();
    lds[t] += add;
    __syncthreads();
  }
  int excl = lds[t] - s;
  for (int i = 0; i < PT; i++) {
    int idx = base + i;
    if (idx < N_NODES) {
      int d = deg[idx];  // L2-hot re-read
      row_start[idx] = excl;
      dinv[idx] = rsqrtf((float)(d + 1));  // +1 self-loop
      excl += d;
    }
  }
  if (t == 1023) row_start[N_NODES] = lds[1023];
}

__global__ void k_fill(const int* __restrict__ src, const int* __restrict__ dst,
                       const int* __restrict__ row_start, int* __restrict__ cursor,
                       int* __restrict__ csr) {
  int e = blockIdx.x * blockDim.x + threadIdx.x;
  if (e < N_EDGES) {
    int d = dst[e];
    int pos = atomicAdd(&cursor[d], 1);
    csr[row_start[d] + pos] = src[e];
  }
}

// ---------------- MFMA split-bf16 GEMM v3 ----------------
// T[n][j] = (sum_k X[n][k] W[j][k] (+bias[j])) * dinv[n], bf16 out.
// acc = Xh*Wh + Xh*Wl + Xl*Wh (fp32 MFMA acc).
// Block: 32 nodes x 128 j, 4 waves; wave wv owns j in [32wv,32wv+32).
// Full-K X tile staged once (ONE barrier); W in VGPRs from L2 (no LDS).
template <int KDIM, bool GATHER, bool HAS_BIAS>
__global__ __launch_bounds__(256) void k_gemm_v3(
    const ushort_t* __restrict__ Xh, const ushort_t* __restrict__ Xl,
    const void* __restrict__ Xv, const int* __restrict__ tokens,
    const int* __restrict__ flags,
    const ushort_t* __restrict__ Wh, const ushort_t* __restrict__ Wl,
    const float* __restrict__ bias, const float* __restrict__ dinvp,
    ushort_t* __restrict__ OutT) {
  constexpr int XS = KDIM + 8;  // row stride (ushorts), 16B-aligned rows
  __shared__ __align__(16) ushort_t xh_lds[32 * XS];
  __shared__ __align__(16) ushort_t xl_lds[32 * XS];

  int tid = threadIdx.x;
  int lane = tid & 63;
  int wv = tid >> 6;
  int node0 = blockIdx.x * 32;
  int fm = lane & 31;
  int fq = lane >> 5;

  // ---- stage full-K X tile ----
  if (GATHER) {
    constexpr int NT = (32 * KDIM / 4) / 256;  // 4-elem segments per thread
    int fl = flags[0];
    if (fl) {  // bf16 table: hi = value, lo = 0 (exact)
      ushort4 v[NT];
      int rows[NT], cs[NT];
#pragma unroll
      for (int i = 0; i < NT; i++) {
        int seg = tid + 256 * i;
        rows[i] = seg / (KDIM / 4);
        cs[i] = seg % (KDIM / 4);
        int tk = tokens[min(node0 + rows[i], N_NODES - 1)];
        v[i] = *(const ushort4*)&((const ushort_t*)Xv)[(size_t)tk * KDIM + 4 * cs[i]];
      }
      ushort4 z; z.x = 0; z.y = 0; z.z = 0; z.w = 0;
#pragma unroll
      for (int i = 0; i < NT; i++) {
        *(ushort4*)&xh_lds[rows[i] * XS + 4 * cs[i]] = v[i];
        *(ushort4*)&xl_lds[rows[i] * XS + 4 * cs[i]] = z;
      }
    } else {  // fp32 table: on-the-fly hi/lo split
      float4 v[NT];
      int rows[NT], cs[NT];
#pragma unroll
      for (int i = 0; i < NT; i++) {
        int seg = tid + 256 * i;
        rows[i] = seg / (KDIM / 4);
        cs[i] = seg % (KDIM / 4);
        int tk = tokens[min(node0 + rows[i], N_NODES - 1)];
        v[i] = *(const float4*)&((const float*)Xv)[(size_t)tk * KDIM + 4 * cs[i]];
      }
#pragma unroll
      for (int i = 0; i < NT; i++) {
        ushort4 h, l;
        h.x = f2bf(v[i].x); l.x = f2bf(v[i].x - bf2f(h.x));
        h.y = f2bf(v[i].y); l.y = f2bf(v[i].y - bf2f(h.y));
        h.z = f2bf(v[i].z); l.z = f2bf(v[i].z - bf2f(h.z));
        h.w = f2bf(v[i].w); l.w = f2bf(v[i].w - bf2f(h.w));
        *(ushort4*)&xh_lds[rows[i] * XS + 4 * cs[i]] = h;
        *(ushort4*)&xl_lds[rows[i] * XS + 4 * cs[i]] = l;
      }
    }
  } else {  // pre-split hi/lo inputs, contiguous uint4 segments
    constexpr int NT = (2 * 32 * KDIM / 8) / 256;
    uint4 v[NT];
    int rows[NT], cs[NT], isl[NT];
#pragma unroll
    for (int i = 0; i < NT; i++) {
      int seg = tid + 256 * i;
      int half = 32 * KDIM / 8;
      int hseg = seg % half;
      isl[i] = seg / half;
      rows[i] = hseg / (KDIM / 8);
      cs[i] = hseg % (KDIM / 8);
      const ushort_t* srcp = isl[i] ? Xl : Xh;
      int n = min(node0 + rows[i], N_NODES - 1);
      v[i] = *(const uint4*)&srcp[(size_t)n * KDIM + 8 * cs[i]];
    }
#pragma unroll
    for (int i = 0; i < NT; i++) {
      ushort_t* dstp = isl[i] ? xl_lds : xh_lds;
      *(uint4*)&dstp[rows[i] * XS + 8 * cs[i]] = v[i];
    }
  }
  __syncthreads();

  f32x16 acc;
#pragma unroll
  for (int r = 0; r < 16; r++) acc[r] = 0.f;

  int j = wv * 32 + fm;
#pragma unroll
  for (int kh = 0; kh < KDIM / 128; kh++) {
    const ushort_t* ph = &Wh[(size_t)j * KDIM + kh * 128 + fq * 8];
    const ushort_t* pl = &Wl[(size_t)j * KDIM + kh * 128 + fq * 8];
    bf16x8 wbh[8], wbl[8];
#pragma unroll
    for (int t = 0; t < 8; t++) {
      wbh[t] = *(const bf16x8*)(ph + t * 16);
      wbl[t] = *(const bf16x8*)(pl + t * 16);
    }
#pragma unroll
    for (int t = 0; t < 8; t++) {
      int ko = kh * 128 + t * 16 + fq * 8;
      bf16x8 ah = *(const bf16x8*)&xh_lds[fm * XS + ko];
      bf16x8 al = *(const bf16x8*)&xl_lds[fm * XS + ko];
      acc = __builtin_amdgcn_mfma_f32_32x32x16_bf16(ah, wbh[t], acc, 0, 0, 0);
      acc = __builtin_amdgcn_mfma_f32_32x32x16_bf16(ah, wbl[t], acc, 0, 0, 0);
      acc = __builtin_amdgcn_mfma_f32_32x32x16_bf16(al, wbh[t], acc, 0, 0, 0);
    }
  }
  // epilogue: C/D col=lane&31, row=(r&3)+8*(r>>2)+4*fq
  float bv = HAS_BIAS ? bias[j] : 0.f;
#pragma unroll
  for (int r = 0; r < 16; r++) {
    int row = (r & 3) + 8 * (r >> 2) + 4 * fq;
    int node = node0 + row;
    if (node < N_NODES)
      OutT[(size_t)node * D + j] = f2bf((acc[r] + bv) * dinvp[node]);
  }
}

// ---------------- aggregation ----------------
// T pre-scaled by dinv: out[d] = dinv[d]*(T[d] + sum_{s->d} T[s]) + b.
template <bool RELU, bool SPLIT_OUT>
__global__ __launch_bounds__(256) void k_aggregate(
    const ushort_t* __restrict__ t, const int* __restrict__ row_start,
    const int* __restrict__ csr, const float* __restrict__ dinv,
    const float* __restrict__ bias, float* __restrict__ out_f,
    ushort_t* __restrict__ outH, ushort_t* __restrict__ outL) {
  int wave = threadIdx.x >> 6;
  int lane = threadIdx.x & 63;
  int node = blockIdx.x * 4 + wave;
  if (node >= N_NODES) return;
  const unsigned int* tu = (const unsigned int*)t;
  float ax, ay;
  {
    unsigned int u = tu[(size_t)node * 64 + lane];  // self-loop (pre-scaled)
    ax = bf2f((ushort_t)(u & 0xFFFF));
    ay = bf2f((ushort_t)(u >> 16));
  }
  int e0 = row_start[node], e1 = row_start[node + 1];
  for (int base = e0; base < e1; base += 64) {
    int cnt = min(64, e1 - base);
    int sidx = (lane < cnt) ? csr[base + lane] : 0;
    int i = 0;
    for (; i + 4 <= cnt; i += 4) {
      int s0 = __shfl(sidx, i);
      int s1 = __shfl(sidx, i + 1);
      int s2 = __shfl(sidx, i + 2);
      int s3 = __shfl(sidx, i + 3);
      unsigned int u0 = tu[(size_t)s0 * 64 + lane];
      unsigned int u1 = tu[(size_t)s1 * 64 + lane];
      unsigned int u2 = tu[(size_t)s2 * 64 + lane];
      unsigned int u3 = tu[(size_t)s3 * 64 + lane];
      ax += bf2f((ushort_t)(u0 & 0xFFFF));
      ay += bf2f((ushort_t)(u0 >> 16));
      ax += bf2f((ushort_t)(u1 & 0xFFFF));
      ay += bf2f((ushort_t)(u1 >> 16));
      ax += bf2f((ushort_t)(u2 & 0xFFFF));
      ay += bf2f((ushort_t)(u2 >> 16));
      ax += bf2f((ushort_t)(u3 & 0xFFFF));
      ay += bf2f((ushort_t)(u3 >> 16));
    }
    for (; i < cnt; i++) {
      int s = __shfl(sidx, i);
      unsigned int u = tu[(size_t)s * 64 + lane];
      ax += bf2f((ushort_t)(u & 0xFFFF));
      ay += bf2f((ushort_t)(u >> 16));
    }
  }
  float di = dinv[node];
  ax = di * ax + bias[2 * lane];
  ay = di * ay + bias[2 * lane + 1];
  if (RELU) {
    ax = fmaxf(ax, 0.f);
    ay = fmaxf(ay, 0.f);
  }
  if (SPLIT_OUT) {
    ushort2 h, l;
    h.x = f2bf(ax); l.x = f2bf(ax - bf2f(h.x));
    h.y = f2bf(ay); l.y = f2bf(ay - bf2f(h.y));
    *(ushort2*)&outH[(size_t)node * D + 2 * lane] = h;
    *(ushort2*)&outL[(size_t)node * D + 2 * lane] = l;
  } else {
    float2 o; o.x = ax; o.y = ay;
    *(float2*)&out_f[(size_t)node * D + 2 * lane] = o;
  }
}

extern "C" void kernel_launch(void* const* d_in, const int* in_sizes, int n_in,
                              void* d_out, int out_size, void* d_ws, size_t ws_size,
                              hipStream_t stream) {
  const int* tokens = (const int*)d_in[0];
  const int* edge = (const int*)d_in[1];  // [2][E]
  const void* embed = d_in[2];
  const void* Wn = d_in[3];
  const void* bn = d_in[4];
  const void* w1 = d_in[5];
  const void* b1 = d_in[6];
  const void* w2 = d_in[7];
  const void* b2 = d_in[8];
  float* out = (float*)d_out;  // fp32 output

  const int* src = edge;
  const int* dst = edge + N_EDGES;

  char* ws = (char*)d_ws;
  ushort_t* Xh = (ushort_t*)ws;                    // 12,800,000 B
  ushort_t* Xl = (ushort_t*)(ws + 12800000);       // 12,800,000 B
  ushort_t* T  = (ushort_t*)(ws + 25600000);       // 12,800,000 B
  float* dinv = (float*)(ws + 38400000);           // 200,000 B
  int* row_start = (int*)(ws + 38600064);          // 200,004 B (pad)
  int* degcur = (int*)(ws + 38800128);             // 400,000 B (deg | cursor)
  int* csr = (int*)(ws + 39200128);                // 2,400,000 B
  int* flags = (int*)(ws + 41600192);              // 28 B
  ushort_t* WcH = (ushort_t*)(ws + 41600256);      // 65,536 B
  ushort_t* WcL = (ushort_t*)(ws + 41665792);      // 65,536 B
  ushort_t* w2H = (ushort_t*)(ws + 41731328);      // 32,768 B
  ushort_t* w2L = (ushort_t*)(ws + 41764096);      // 32,768 B
  float* bias_ws = (float*)(ws + 41796864);        // bc | b1 | b2 (1,536 B)
  float* bcf = bias_ws;
  float* b1f = bias_ws + 128;
  float* b2f = bias_ws + 256;
  int* deg = degcur;
  int* cursor = degcur + N_NODES;

  const int GGRID = (N_NODES + 31) / 32;  // 1563

  // --- dtype detect; fused W precompute; w2 split; biases ---
  k_detect<<<1, 256, 0, stream>>>(embed, Wn, bn, w1, b1, w2, b2, flags);
  k_split<<<(16640 + 255) / 256, 256, 0, stream>>>(w2, b1, b2, flags, w2H, w2L, b1f, b2f);
  k_wc<<<128, 256, 0, stream>>>(Wn, w1, bn, flags, WcH, WcL, bcf);

  // --- CSR build ---
  hipMemsetAsync(degcur, 0, 2 * N_NODES * sizeof(int), stream);
  k_deg<<<(N_EDGES + 255) / 256, 256, 0, stream>>>(dst, deg);
  k_scan_all<<<1, 1024, 0, stream>>>(deg, row_start, dinv);
  k_fill<<<(N_EDGES + 255) / 256, 256, 0, stream>>>(src, dst, row_start, cursor, csr);

  // --- conv1 (fused embed): T = (gather(e) @ Wc^T + bc)*dinv ---
  k_gemm_v3<D_IN, true, true><<<GGRID, 256, 0, stream>>>(
      nullptr, nullptr, embed, tokens, flags, WcH, WcL, bcf, dinv, T);
  k_aggregate<true, true><<<(N_NODES + 3) / 4, 256, 0, stream>>>(
      T, row_start, csr, dinv, b1f, nullptr, Xh, Xl);

  // --- conv2: T = (x1 @ w2^T)*dinv ; aggregate + b2 -> out ---
  k_gemm_v3<D, false, false><<<GGRID, 256, 0, stream>>>(
      Xh, Xl, nullptr, nullptr, nullptr, w2H, w2L, nullptr, dinv, T);
  k_aggregate<false, false><<<(N_NODES + 3) / 4, 256, 0, stream>>>(
      T, row_start, csr, dinv, b2f, out, nullptr, nullptr);
}

// Round 10
// 342.666 us; speedup vs baseline: 1.3224x; 1.3224x over previous
//
#include <hip/hip_runtime.h>
#include <hip/hip_bf16.h>

#define N_NODES 50000
#define N_EDGES 600000
#define D_IN 256
#define D 128

#define SCAN_CHUNK 1024
#define N_CHUNKS ((N_NODES + SCAN_CHUNK - 1) / SCAN_CHUNK)  // 49

typedef unsigned short ushort_t;
typedef __attribute__((ext_vector_type(8))) short bf16x8;
typedef __attribute__((ext_vector_type(16))) float f32x16;

__device__ __forceinline__ float bf2f(ushort_t u) {
  union { unsigned int i; float f; } v;
  v.i = ((unsigned int)u) << 16;
  return v.f;
}
__device__ __forceinline__ ushort_t f2bf(float f) {
  union { float f; unsigned int i; } v;
  v.f = f;
  unsigned int x = v.i;
  unsigned int r = (x + 0x7FFFu + ((x >> 16) & 1u)) >> 16;  // RNE
  return (ushort_t)r;
}

// ---------------- dtype detection (insurance; expected all-fp32) ----------------
__global__ void k_detect(const void* e, const void* wn, const void* bn,
                         const void* w1, const void* b1, const void* w2,
                         const void* b2, int* flags) {
  const void* ptrs[7] = {e, wn, bn, w1, b1, w2, b2};
  const int ns[7] = {12800000, 32768, 128, 16384, 128, 16384, 128};
  __shared__ int red[256];
  int t = threadIdx.x;
  for (int a = 0; a < 7; a++) {
    int pn = ns[a] < 2048 ? ns[a] : 2048;
    const ushort_t* p = (const ushort_t*)ptrs[a];
    int cnt = 0;
    for (int i = t; i < pn; i += 256) {
      ushort_t u = p[i];
      int ex = (u >> 7) & 0xFF;
      if ((u & 0x7FFF) == 0 || (ex >= 100 && ex <= 130)) cnt++;
    }
    red[t] = cnt;
    __syncthreads();
    for (int off = 128; off > 0; off >>= 1) {
      if (t < off) red[t] += red[t + off];
      __syncthreads();
    }
    if (t == 0) flags[a] = (red[0] * 100 >= pn * 85) ? 1 : 0;
    __syncthreads();
  }
}

// Split w2 into bf16 hi/lo; canonicalize b1/b2 to fp32.
__global__ void k_split(const void* w2, const void* b1, const void* b2,
                        const int* __restrict__ flags,
                        ushort_t* __restrict__ w2H, ushort_t* __restrict__ w2L,
                        float* __restrict__ b1f, float* __restrict__ b2f) {
  int i = blockIdx.x * blockDim.x + threadIdx.x;
  if (i >= 16640) return;
  if (i < 16384) {
    int fl = flags[5];
    float v = fl ? bf2f(((const ushort_t*)w2)[i]) : ((const float*)w2)[i];
    ushort_t h = f2bf(v);
    w2H[i] = h;
    w2L[i] = f2bf(v - bf2f(h));
  } else if (i < 16512) {
    int j = i - 16384;
    b1f[j] = flags[4] ? bf2f(((const ushort_t*)b1)[j]) : ((const float*)b1)[j];
  } else {
    int j = i - 16512;
    b2f[j] = flags[6] ? bf2f(((const ushort_t*)b2)[j]) : ((const float*)b2)[j];
  }
}

// Fused first-layer weight: Wc = w1 @ Wn  ([128,256]), bc = w1 @ bn.
// t1 = (e@Wn^T + bn)@w1^T  ==  e@Wc^T + bc   (exact algebra).
__global__ __launch_bounds__(256) void k_wc(
    const void* wn, const void* w1, const void* bn, const int* __restrict__ flags,
    ushort_t* __restrict__ WcH, ushort_t* __restrict__ WcL, float* __restrict__ bc) {
  int j = blockIdx.x;   // 0..127
  int k = threadIdx.x;  // 0..255
  int flWn = flags[1], flW1 = flags[3], flBn = flags[2];
  float acc = 0.f;
  for (int m = 0; m < 128; m++) {
    float a = flW1 ? bf2f(((const ushort_t*)w1)[j * 128 + m])
                   : ((const float*)w1)[j * 128 + m];
    float b = flWn ? bf2f(((const ushort_t*)wn)[m * 256 + k])
                   : ((const float*)wn)[m * 256 + k];
    acc += a * b;
  }
  ushort_t h = f2bf(acc);
  WcH[j * 256 + k] = h;
  WcL[j * 256 + k] = f2bf(acc - bf2f(h));
  if (k == 0) {
    float s = 0.f;
    for (int m = 0; m < 128; m++) {
      float a = flW1 ? bf2f(((const ushort_t*)w1)[j * 128 + m])
                     : ((const float*)w1)[j * 128 + m];
      float b = flBn ? bf2f(((const ushort_t*)bn)[m]) : ((const float*)bn)[m];
      s += a * b;
    }
    bc[j] = s;
  }
}

// ---------------- CSR build (hierarchical scan; R8 structure) ----------------

__global__ void k_deg(const int* __restrict__ dst, int* __restrict__ deg) {
  int e = blockIdx.x * blockDim.x + threadIdx.x;
  if (e < N_EDGES) atomicAdd(&deg[dst[e]], 1);
}

__global__ void k_partial(const int* __restrict__ deg, int* __restrict__ partial) {
  __shared__ int lds[256];
  int b = blockIdx.x, t = threadIdx.x;
  int base = b * SCAN_CHUNK + t * 4;
  int s = 0;
#pragma unroll
  for (int i = 0; i < 4; i++) {
    int idx = base + i;
    if (idx < N_NODES) s += deg[idx];
  }
  lds[t] = s;
  __syncthreads();
  for (int off = 128; off > 0; off >>= 1) {
    if (t < off) lds[t] += lds[t + off];
    __syncthreads();
  }
  if (t == 0) partial[b] = lds[0];
}

__global__ void k_scan_part(int* __restrict__ partial, int* __restrict__ row_start) {
  if (threadIdx.x == 0) {
    int run = 0;
    for (int i = 0; i < N_CHUNKS; i++) {
      int v = partial[i];
      partial[i] = run;
      run += v;
    }
    row_start[N_NODES] = run;  // == N_EDGES
  }
}

__global__ void k_scan_final(const int* __restrict__ deg, const int* __restrict__ partial,
                             int* __restrict__ row_start, float* __restrict__ dinv) {
  __shared__ int lds[256];
  int b = blockIdx.x, t = threadIdx.x;
  int base = b * SCAN_CHUNK + t * 4;
  int v[4];
  int s = 0;
#pragma unroll
  for (int i = 0; i < 4; i++) {
    int idx = base + i;
    v[i] = (idx < N_NODES) ? deg[idx] : 0;
    s += v[i];
  }
  lds[t] = s;
  __syncthreads();
  for (int off = 1; off < 256; off <<= 1) {
    int add = (t >= off) ? lds[t - off] : 0;
    __syncthreads();
    lds[t] += add;
    __syncthreads();
  }
  int excl = lds[t] - s + partial[b];
#pragma unroll
  for (int i = 0; i < 4; i++) {
    int idx = base + i;
    if (idx < N_NODES) {
      row_start[idx] = excl;
      dinv[idx] = rsqrtf((float)(v[i] + 1));  // +1 self-loop
      excl += v[i];
    }
  }
}

__global__ void k_fill(const int* __restrict__ src, const int* __restrict__ dst,
                       const int* __restrict__ row_start, int* __restrict__ cursor,
                       int* __restrict__ csr) {
  int e = blockIdx.x * blockDim.x + threadIdx.x;
  if (e < N_EDGES) {
    int d = dst[e];
    int pos = atomicAdd(&cursor[d], 1);
    csr[row_start[d] + pos] = src[e];
  }
}

// ---------------- MFMA split-bf16 GEMM v3 ----------------
// T[n][j] = (sum_k X[n][k] W[j][k] (+bias[j])) * dinv[n], bf16 out.
// acc = Xh*Wh + Xh*Wl + Xl*Wh (fp32 MFMA acc).
// Block: 32 nodes x 128 j, 4 waves; wave wv owns j in [32wv,32wv+32).
// Full-K X tile staged once (ONE barrier); W in VGPRs from L2 (no LDS).
template <int KDIM, bool GATHER, bool HAS_BIAS>
__global__ __launch_bounds__(256) void k_gemm_v3(
    const ushort_t* __restrict__ Xh, const ushort_t* __restrict__ Xl,
    const void* __restrict__ Xv, const int* __restrict__ tokens,
    const int* __restrict__ flags,
    const ushort_t* __restrict__ Wh, const ushort_t* __restrict__ Wl,
    const float* __restrict__ bias, const float* __restrict__ dinvp,
    ushort_t* __restrict__ OutT) {
  constexpr int XS = KDIM + 8;  // row stride (ushorts), 16B-aligned rows
  __shared__ __align__(16) ushort_t xh_lds[32 * XS];
  __shared__ __align__(16) ushort_t xl_lds[32 * XS];

  int tid = threadIdx.x;
  int lane = tid & 63;
  int wv = tid >> 6;
  int node0 = blockIdx.x * 32;
  int fm = lane & 31;
  int fq = lane >> 5;

  // ---- stage full-K X tile ----
  if (GATHER) {
    constexpr int NT = (32 * KDIM / 4) / 256;  // 4-elem segments per thread
    int fl = flags[0];
    if (fl) {  // bf16 table: hi = value, lo = 0 (exact)
      ushort4 v[NT];
      int rows[NT], cs[NT];
#pragma unroll
      for (int i = 0; i < NT; i++) {
        int seg = tid + 256 * i;
        rows[i] = seg / (KDIM / 4);
        cs[i] = seg % (KDIM / 4);
        int tk = tokens[min(node0 + rows[i], N_NODES - 1)];
        v[i] = *(const ushort4*)&((const ushort_t*)Xv)[(size_t)tk * KDIM + 4 * cs[i]];
      }
      ushort4 z; z.x = 0; z.y = 0; z.z = 0; z.w = 0;
#pragma unroll
      for (int i = 0; i < NT; i++) {
        *(ushort4*)&xh_lds[rows[i] * XS + 4 * cs[i]] = v[i];
        *(ushort4*)&xl_lds[rows[i] * XS + 4 * cs[i]] = z;
      }
    } else {  // fp32 table: on-the-fly hi/lo split
      float4 v[NT];
      int rows[NT], cs[NT];
#pragma unroll
      for (int i = 0; i < NT; i++) {
        int seg = tid + 256 * i;
        rows[i] = seg / (KDIM / 4);
        cs[i] = seg % (KDIM / 4);
        int tk = tokens[min(node0 + rows[i], N_NODES - 1)];
        v[i] = *(const float4*)&((const float*)Xv)[(size_t)tk * KDIM + 4 * cs[i]];
      }
#pragma unroll
      for (int i = 0; i < NT; i++) {
        ushort4 h, l;
        h.x = f2bf(v[i].x); l.x = f2bf(v[i].x - bf2f(h.x));
        h.y = f2bf(v[i].y); l.y = f2bf(v[i].y - bf2f(h.y));
        h.z = f2bf(v[i].z); l.z = f2bf(v[i].z - bf2f(h.z));
        h.w = f2bf(v[i].w); l.w = f2bf(v[i].w - bf2f(h.w));
        *(ushort4*)&xh_lds[rows[i] * XS + 4 * cs[i]] = h;
        *(ushort4*)&xl_lds[rows[i] * XS + 4 * cs[i]] = l;
      }
    }
  } else {  // pre-split hi/lo inputs, contiguous uint4 segments
    constexpr int NT = (2 * 32 * KDIM / 8) / 256;
    uint4 v[NT];
    int rows[NT], cs[NT], isl[NT];
#pragma unroll
    for (int i = 0; i < NT; i++) {
      int seg = tid + 256 * i;
      int half = 32 * KDIM / 8;
      int hseg = seg % half;
      isl[i] = seg / half;
      rows[i] = hseg / (KDIM / 8);
      cs[i] = hseg % (KDIM / 8);
      const ushort_t* srcp = isl[i] ? Xl : Xh;
      int n = min(node0 + rows[i], N_NODES - 1);
      v[i] = *(const uint4*)&srcp[(size_t)n * KDIM + 8 * cs[i]];
    }
#pragma unroll
    for (int i = 0; i < NT; i++) {
      ushort_t* dstp = isl[i] ? xl_lds : xh_lds;
      *(uint4*)&dstp[rows[i] * XS + 8 * cs[i]] = v[i];
    }
  }
  __syncthreads();

  f32x16 acc;
#pragma unroll
  for (int r = 0; r < 16; r++) acc[r] = 0.f;

  int j = wv * 32 + fm;
#pragma unroll
  for (int kh = 0; kh < KDIM / 128; kh++) {
    const ushort_t* ph = &Wh[(size_t)j * KDIM + kh * 128 + fq * 8];
    const ushort_t* pl = &Wl[(size_t)j * KDIM + kh * 128 + fq * 8];
    bf16x8 wbh[8], wbl[8];
#pragma unroll
    for (int t = 0; t < 8; t++) {
      wbh[t] = *(const bf16x8*)(ph + t * 16);
      wbl[t] = *(const bf16x8*)(pl + t * 16);
    }
#pragma unroll
    for (int t = 0; t < 8; t++) {
      int ko = kh * 128 + t * 16 + fq * 8;
      bf16x8 ah = *(const bf16x8*)&xh_lds[fm * XS + ko];
      bf16x8 al = *(const bf16x8*)&xl_lds[fm * XS + ko];
      acc = __builtin_amdgcn_mfma_f32_32x32x16_bf16(ah, wbh[t], acc, 0, 0, 0);
      acc = __builtin_amdgcn_mfma_f32_32x32x16_bf16(ah, wbl[t], acc, 0, 0, 0);
      acc = __builtin_amdgcn_mfma_f32_32x32x16_bf16(al, wbh[t], acc, 0, 0, 0);
    }
  }
  // epilogue: C/D col=lane&31, row=(r&3)+8*(r>>2)+4*fq
  float bv = HAS_BIAS ? bias[j] : 0.f;
#pragma unroll
  for (int r = 0; r < 16; r++) {
    int row = (r & 3) + 8 * (r >> 2) + 4 * fq;
    int node = node0 + row;
    if (node < N_NODES)
      OutT[(size_t)node * D + j] = f2bf((acc[r] + bv) * dinvp[node]);
  }
}

// ---------------- aggregation ----------------
// T pre-scaled by dinv: out[d] = dinv[d]*(T[d] + sum_{s->d} T[s]) + b.
template <bool RELU, bool SPLIT_OUT>
__global__ __launch_bounds__(256) void k_aggregate(
    const ushort_t* __restrict__ t, const int* __restrict__ row_start,
    const int* __restrict__ csr, const float* __restrict__ dinv,
    const float* __restrict__ bias, float* __restrict__ out_f,
    ushort_t* __restrict__ outH, ushort_t* __restrict__ outL) {
  int wave = threadIdx.x >> 6;
  int lane = threadIdx.x & 63;
  int node = blockIdx.x * 4 + wave;
  if (node >= N_NODES) return;
  const unsigned int* tu = (const unsigned int*)t;
  float ax, ay;
  {
    unsigned int u = tu[(size_t)node * 64 + lane];  // self-loop (pre-scaled)
    ax = bf2f((ushort_t)(u & 0xFFFF));
    ay = bf2f((ushort_t)(u >> 16));
  }
  int e0 = row_start[node], e1 = row_start[node + 1];
  for (int base = e0; base < e1; base += 64) {
    int cnt = min(64, e1 - base);
    int sidx = (lane < cnt) ? csr[base + lane] : 0;
    int i = 0;
    for (; i + 4 <= cnt; i += 4) {
      int s0 = __shfl(sidx, i);
      int s1 = __shfl(sidx, i + 1);
      int s2 = __shfl(sidx, i + 2);
      int s3 = __shfl(sidx, i + 3);
      unsigned int u0 = tu[(size_t)s0 * 64 + lane];
      unsigned int u1 = tu[(size_t)s1 * 64 + lane];
      unsigned int u2 = tu[(size_t)s2 * 64 + lane];
      unsigned int u3 = tu[(size_t)s3 * 64 + lane];
      ax += bf2f((ushort_t)(u0 & 0xFFFF));
      ay += bf2f((ushort_t)(u0 >> 16));
      ax += bf2f((ushort_t)(u1 & 0xFFFF));
      ay += bf2f((ushort_t)(u1 >> 16));
      ax += bf2f((ushort_t)(u2 & 0xFFFF));
      ay += bf2f((ushort_t)(u2 >> 16));
      ax += bf2f((ushort_t)(u3 & 0xFFFF));
      ay += bf2f((ushort_t)(u3 >> 16));
    }
    for (; i < cnt; i++) {
      int s = __shfl(sidx, i);
      unsigned int u = tu[(size_t)s * 64 + lane];
      ax += bf2f((ushort_t)(u & 0xFFFF));
      ay += bf2f((ushort_t)(u >> 16));
    }
  }
  float di = dinv[node];
  ax = di * ax + bias[2 * lane];
  ay = di * ay + bias[2 * lane + 1];
  if (RELU) {
    ax = fmaxf(ax, 0.f);
    ay = fmaxf(ay, 0.f);
  }
  if (SPLIT_OUT) {
    ushort2 h, l;
    h.x = f2bf(ax); l.x = f2bf(ax - bf2f(h.x));
    h.y = f2bf(ay); l.y = f2bf(ay - bf2f(h.y));
    *(ushort2*)&outH[(size_t)node * D + 2 * lane] = h;
    *(ushort2*)&outL[(size_t)node * D + 2 * lane] = l;
  } else {
    float2 o; o.x = ax; o.y = ay;
    *(float2*)&out_f[(size_t)node * D + 2 * lane] = o;
  }
}

extern "C" void kernel_launch(void* const* d_in, const int* in_sizes, int n_in,
                              void* d_out, int out_size, void* d_ws, size_t ws_size,
                              hipStream_t stream) {
  const int* tokens = (const int*)d_in[0];
  const int* edge = (const int*)d_in[1];  // [2][E]
  const void* embed = d_in[2];
  const void* Wn = d_in[3];
  const void* bn = d_in[4];
  const void* w1 = d_in[5];
  const void* b1 = d_in[6];
  const void* w2 = d_in[7];
  const void* b2 = d_in[8];
  float* out = (float*)d_out;  // fp32 output

  const int* src = edge;
  const int* dst = edge + N_EDGES;

  char* ws = (char*)d_ws;
  ushort_t* Xh = (ushort_t*)ws;                    // 12,800,000 B
  ushort_t* Xl = (ushort_t*)(ws + 12800000);       // 12,800,000 B
  ushort_t* T  = (ushort_t*)(ws + 25600000);       // 12,800,000 B
  float* dinv = (float*)(ws + 38400000);           // 200,000 B
  int* row_start = (int*)(ws + 38600064);          // 200,004 B (pad)
  int* degcur = (int*)(ws + 38800128);             // 400,000 B (deg | cursor)
  int* csr = (int*)(ws + 39200128);                // 2,400,000 B
  int* partial = (int*)(ws + 41600192);            // 196 B
  int* flags = (int*)(ws + 41600448);              // 28 B
  ushort_t* WcH = (ushort_t*)(ws + 41600512);      // 65,536 B
  ushort_t* WcL = (ushort_t*)(ws + 41666048);      // 65,536 B
  ushort_t* w2H = (ushort_t*)(ws + 41731584);      // 32,768 B
  ushort_t* w2L = (ushort_t*)(ws + 41764352);      // 32,768 B
  float* bias_ws = (float*)(ws + 41797120);        // bc | b1 | b2 (1,536 B)
  float* bcf = bias_ws;
  float* b1f = bias_ws + 128;
  float* b2f = bias_ws + 256;
  int* deg = degcur;
  int* cursor = degcur + N_NODES;

  const int GGRID = (N_NODES + 31) / 32;  // 1563

  // --- dtype detect; fused W precompute; w2 split; biases ---
  k_detect<<<1, 256, 0, stream>>>(embed, Wn, bn, w1, b1, w2, b2, flags);
  k_split<<<(16640 + 255) / 256, 256, 0, stream>>>(w2, b1, b2, flags, w2H, w2L, b1f, b2f);
  k_wc<<<128, 256, 0, stream>>>(Wn, w1, bn, flags, WcH, WcL, bcf);

  // --- CSR build (hierarchical scan) ---
  hipMemsetAsync(degcur, 0, 2 * N_NODES * sizeof(int), stream);
  k_deg<<<(N_EDGES + 255) / 256, 256, 0, stream>>>(dst, deg);
  k_partial<<<N_CHUNKS, 256, 0, stream>>>(deg, partial);
  k_scan_part<<<1, 64, 0, stream>>>(partial, row_start);
  k_scan_final<<<N_CHUNKS, 256, 0, stream>>>(deg, partial, row_start, dinv);
  k_fill<<<(N_EDGES + 255) / 256, 256, 0, stream>>>(src, dst, row_start, cursor, csr);

  // --- conv1 (fused embed): T = (gather(e) @ Wc^T + bc)*dinv ---
  k_gemm_v3<D_IN, true, true><<<GGRID, 256, 0, stream>>>(
      nullptr, nullptr, embed, tokens, flags, WcH, WcL, bcf, dinv, T);
  k_aggregate<true, true><<<(N_NODES + 3) / 4, 256, 0, stream>>>(
      T, row_start, csr, dinv, b1f, nullptr, Xh, Xl);

  // --- conv2: T = (x1 @ w2^T)*dinv ; aggregate + b2 -> out ---
  k_gemm_v3<D, false, false><<<GGRID, 256, 0, stream>>>(
      Xh, Xl, nullptr, nullptr, nullptr, w2H, w2L, nullptr, dinv, T);
  k_aggregate<false, false><<<(N_NODES + 3) / 4, 256, 0, stream>>>(
      T, row_start, csr, dinv, b2f, out, nullptr, nullptr);
}

// Round 11
// 317.621 us; speedup vs baseline: 1.4267x; 1.0789x over previous
//
#include <hip/hip_runtime.h>
#include <hip/hip_bf16.h>

#define N_NODES 50000
#define N_EDGES 600000
#define D_IN 256
#define D 128

#define SCAN_CHUNK 1024
#define N_CHUNKS ((N_NODES + SCAN_CHUNK - 1) / SCAN_CHUNK)  // 49

typedef unsigned short ushort_t;
typedef __attribute__((ext_vector_type(8))) short bf16x8;
typedef __attribute__((ext_vector_type(16))) float f32x16;

__device__ __forceinline__ float bf2f(ushort_t u) {
  union { unsigned int i; float f; } v;
  v.i = ((unsigned int)u) << 16;
  return v.f;
}
__device__ __forceinline__ ushort_t f2bf(float f) {
  union { float f; unsigned int i; } v;
  v.f = f;
  unsigned int x = v.i;
  unsigned int r = (x + 0x7FFFu + ((x >> 16) & 1u)) >> 16;  // RNE
  return (ushort_t)r;
}

// Swizzled-W addressing: element (j,k) of a [128,KDIM] W, split hi/lo, lives at
//   wv=j>>5, fm=j&31, kh=k>>7, t=(k>>4)&7, fq=(k>>3)&1, c=k&7, lane=fq*32+fm
//   addr = (((wv*(KDIM/128)+kh)*8 + t)*2 + hl)*512 + lane*8 + c   [ushorts]
// so a wave's fragment load is base + lane*8 -> perfectly coalesced.

// ---------------- dtype detection (insurance; expected all-fp32) ----------------
__global__ void k_detect(const void* e, const void* wn, const void* bn,
                         const void* w1, const void* b1, const void* w2,
                         const void* b2, int* flags) {
  const void* ptrs[7] = {e, wn, bn, w1, b1, w2, b2};
  const int ns[7] = {12800000, 32768, 128, 16384, 128, 16384, 128};
  __shared__ int red[256];
  int t = threadIdx.x;
  for (int a = 0; a < 7; a++) {
    int pn = ns[a] < 2048 ? ns[a] : 2048;
    const ushort_t* p = (const ushort_t*)ptrs[a];
    int cnt = 0;
    for (int i = t; i < pn; i += 256) {
      ushort_t u = p[i];
      int ex = (u >> 7) & 0xFF;
      if ((u & 0x7FFF) == 0 || (ex >= 100 && ex <= 130)) cnt++;
    }
    red[t] = cnt;
    __syncthreads();
    for (int off = 128; off > 0; off >>= 1) {
      if (t < off) red[t] += red[t + off];
      __syncthreads();
    }
    if (t == 0) flags[a] = (red[0] * 100 >= pn * 85) ? 1 : 0;
    __syncthreads();
  }
}

// w2 -> swizzled hi/lo (KDIM=128); b1/b2 -> fp32.
__global__ void k_split(const void* w2, const void* b1, const void* b2,
                        const int* __restrict__ flags,
                        ushort_t* __restrict__ W2Sw,
                        float* __restrict__ b1f, float* __restrict__ b2f) {
  int i = blockIdx.x * blockDim.x + threadIdx.x;
  if (i >= 16640) return;
  if (i < 16384) {
    int fl = flags[5];
    float v = fl ? bf2f(((const ushort_t*)w2)[i]) : ((const float*)w2)[i];
    ushort_t h = f2bf(v);
    ushort_t l = f2bf(v - bf2f(h));
    int j = i >> 7, k = i & 127;
    int wv = j >> 5, fm = j & 31;
    int t = (k >> 4) & 7, fq = (k >> 3) & 1, c = k & 7;
    int lane = fq * 32 + fm;
    int base = (wv * 8 + t) * 2 * 512 + lane * 8 + c;  // KH=1, kh=0
    W2Sw[base] = h;
    W2Sw[base + 512] = l;
  } else if (i < 16512) {
    int j = i - 16384;
    b1f[j] = flags[4] ? bf2f(((const ushort_t*)b1)[j]) : ((const float*)b1)[j];
  } else {
    int j = i - 16512;
    b2f[j] = flags[6] ? bf2f(((const ushort_t*)b2)[j]) : ((const float*)b2)[j];
  }
}

// Fused first-layer weight: Wc = w1 @ Wn ([128,256]) -> swizzled hi/lo; bc = w1 @ bn.
__global__ __launch_bounds__(256) void k_wc(
    const void* wn, const void* w1, const void* bn, const int* __restrict__ flags,
    ushort_t* __restrict__ WcSw, float* __restrict__ bc) {
  int j = blockIdx.x;   // 0..127
  int k = threadIdx.x;  // 0..255
  int flWn = flags[1], flW1 = flags[3], flBn = flags[2];
  float acc = 0.f;
  for (int m = 0; m < 128; m++) {
    float a = flW1 ? bf2f(((const ushort_t*)w1)[j * 128 + m])
                   : ((const float*)w1)[j * 128 + m];
    float b = flWn ? bf2f(((const ushort_t*)wn)[m * 256 + k])
                   : ((const float*)wn)[m * 256 + k];
    acc += a * b;
  }
  ushort_t h = f2bf(acc);
  ushort_t l = f2bf(acc - bf2f(h));
  int wv = j >> 5, fm = j & 31;
  int kh = k >> 7, t = (k >> 4) & 7, fq = (k >> 3) & 1, c = k & 7;
  int lane = fq * 32 + fm;
  int base = ((wv * 2 + kh) * 8 + t) * 2 * 512 + lane * 8 + c;  // KH=2
  WcSw[base] = h;
  WcSw[base + 512] = l;
  if (k == 0) {
    float s = 0.f;
    for (int m = 0; m < 128; m++) {
      float a = flW1 ? bf2f(((const ushort_t*)w1)[j * 128 + m])
                     : ((const float*)w1)[j * 128 + m];
      float b = flBn ? bf2f(((const ushort_t*)bn)[m]) : ((const float*)bn)[m];
      s += a * b;
    }
    bc[j] = s;
  }
}

// ---------------- CSR build (hierarchical scan) ----------------

__global__ void k_deg(const int* __restrict__ dst, int* __restrict__ deg) {
  int e = blockIdx.x * blockDim.x + threadIdx.x;
  if (e < N_EDGES) atomicAdd(&deg[dst[e]], 1);
}

__global__ void k_partial(const int* __restrict__ deg, int* __restrict__ partial) {
  __shared__ int lds[256];
  int b = blockIdx.x, t = threadIdx.x;
  int base = b * SCAN_CHUNK + t * 4;
  int s = 0;
#pragma unroll
  for (int i = 0; i < 4; i++) {
    int idx = base + i;
    if (idx < N_NODES) s += deg[idx];
  }
  lds[t] = s;
  __syncthreads();
  for (int off = 128; off > 0; off >>= 1) {
    if (t < off) lds[t] += lds[t + off];
    __syncthreads();
  }
  if (t == 0) partial[b] = lds[0];
}

__global__ void k_scan_part(int* __restrict__ partial, int* __restrict__ row_start) {
  if (threadIdx.x == 0) {
    int run = 0;
    for (int i = 0; i < N_CHUNKS; i++) {
      int v = partial[i];
      partial[i] = run;
      run += v;
    }
    row_start[N_NODES] = run;  // == N_EDGES
  }
}

__global__ void k_scan_final(const int* __restrict__ deg, const int* __restrict__ partial,
                             int* __restrict__ row_start, float* __restrict__ dinv) {
  __shared__ int lds[256];
  int b = blockIdx.x, t = threadIdx.x;
  int base = b * SCAN_CHUNK + t * 4;
  int v[4];
  int s = 0;
#pragma unroll
  for (int i = 0; i < 4; i++) {
    int idx = base + i;
    v[i] = (idx < N_NODES) ? deg[idx] : 0;
    s += v[i];
  }
  lds[t] = s;
  __syncthreads();
  for (int off = 1; off < 256; off <<= 1) {
    int add = (t >= off) ? lds[t - off] : 0;
    __syncthreads();
    lds[t] += add;
    __syncthreads();
  }
  int excl = lds[t] - s + partial[b];
#pragma unroll
  for (int i = 0; i < 4; i++) {
    int idx = base + i;
    if (idx < N_NODES) {
      row_start[idx] = excl;
      dinv[idx] = rsqrtf((float)(v[i] + 1));  // +1 self-loop
      excl += v[i];
    }
  }
}

__global__ void k_fill(const int* __restrict__ src, const int* __restrict__ dst,
                       const int* __restrict__ row_start, int* __restrict__ cursor,
                       int* __restrict__ csr) {
  int e = blockIdx.x * blockDim.x + threadIdx.x;
  if (e < N_EDGES) {
    int d = dst[e];
    int pos = atomicAdd(&cursor[d], 1);
    csr[row_start[d] + pos] = src[e];
  }
}

// ---------------- MFMA split-bf16 GEMM v4 (swizzled W) ----------------
// T[n][j] = (sum_k X[n][k] W[j][k] (+bias[j])) * dinv[n], bf16 out.
// W pre-swizzled to fragment order: every W load is base + lane*16B (coalesced,
// L2-hot). X tile staged once to LDS (ONE barrier).
template <int KDIM, bool GATHER, bool HAS_BIAS>
__global__ __launch_bounds__(256) void k_gemm_v4(
    const ushort_t* __restrict__ Xh, const ushort_t* __restrict__ Xl,
    const void* __restrict__ Xv, const int* __restrict__ tokens,
    const int* __restrict__ flags,
    const ushort_t* __restrict__ Wsw,
    const float* __restrict__ bias, const float* __restrict__ dinvp,
    ushort_t* __restrict__ OutT) {
  constexpr int KH = KDIM / 128;
  constexpr int XS = KDIM + 8;  // row stride (ushorts), 16B-aligned rows
  __shared__ __align__(16) ushort_t xh_lds[32 * XS];
  __shared__ __align__(16) ushort_t xl_lds[32 * XS];

  int tid = threadIdx.x;
  int lane = tid & 63;
  int wv = tid >> 6;
  int node0 = blockIdx.x * 32;
  int fm = lane & 31;
  int fq = lane >> 5;

  // ---- stage full-K X tile ----
  if (GATHER) {
    constexpr int NT = (32 * KDIM / 4) / 256;  // 4-elem segments per thread
    int fl = flags[0];
    if (fl) {  // bf16 table: hi = value, lo = 0 (exact)
      ushort4 v[NT];
      int rows[NT], cs[NT];
#pragma unroll
      for (int i = 0; i < NT; i++) {
        int seg = tid + 256 * i;
        rows[i] = seg / (KDIM / 4);
        cs[i] = seg % (KDIM / 4);
        int tk = tokens[min(node0 + rows[i], N_NODES - 1)];
        v[i] = *(const ushort4*)&((const ushort_t*)Xv)[(size_t)tk * KDIM + 4 * cs[i]];
      }
      ushort4 z; z.x = 0; z.y = 0; z.z = 0; z.w = 0;
#pragma unroll
      for (int i = 0; i < NT; i++) {
        *(ushort4*)&xh_lds[rows[i] * XS + 4 * cs[i]] = v[i];
        *(ushort4*)&xl_lds[rows[i] * XS + 4 * cs[i]] = z;
      }
    } else {  // fp32 table: on-the-fly hi/lo split
      float4 v[NT];
      int rows[NT], cs[NT];
#pragma unroll
      for (int i = 0; i < NT; i++) {
        int seg = tid + 256 * i;
        rows[i] = seg / (KDIM / 4);
        cs[i] = seg % (KDIM / 4);
        int tk = tokens[min(node0 + rows[i], N_NODES - 1)];
        v[i] = *(const float4*)&((const float*)Xv)[(size_t)tk * KDIM + 4 * cs[i]];
      }
#pragma unroll
      for (int i = 0; i < NT; i++) {
        ushort4 h, l;
        h.x = f2bf(v[i].x); l.x = f2bf(v[i].x - bf2f(h.x));
        h.y = f2bf(v[i].y); l.y = f2bf(v[i].y - bf2f(h.y));
        h.z = f2bf(v[i].z); l.z = f2bf(v[i].z - bf2f(h.z));
        h.w = f2bf(v[i].w); l.w = f2bf(v[i].w - bf2f(h.w));
        *(ushort4*)&xh_lds[rows[i] * XS + 4 * cs[i]] = h;
        *(ushort4*)&xl_lds[rows[i] * XS + 4 * cs[i]] = l;
      }
    }
  } else {  // pre-split hi/lo inputs, contiguous uint4 segments
    constexpr int NT = (2 * 32 * KDIM / 8) / 256;
    uint4 v[NT];
    int rows[NT], cs[NT], isl[NT];
#pragma unroll
    for (int i = 0; i < NT; i++) {
      int seg = tid + 256 * i;
      int half = 32 * KDIM / 8;
      int hseg = seg % half;
      isl[i] = seg / half;
      rows[i] = hseg / (KDIM / 8);
      cs[i] = hseg % (KDIM / 8);
      const ushort_t* srcp = isl[i] ? Xl : Xh;
      int n = min(node0 + rows[i], N_NODES - 1);
      v[i] = *(const uint4*)&srcp[(size_t)n * KDIM + 8 * cs[i]];
    }
#pragma unroll
    for (int i = 0; i < NT; i++) {
      ushort_t* dstp = isl[i] ? xl_lds : xh_lds;
      *(uint4*)&dstp[rows[i] * XS + 8 * cs[i]] = v[i];
    }
  }
  __syncthreads();

  f32x16 acc;
#pragma unroll
  for (int r = 0; r < 16; r++) acc[r] = 0.f;

#pragma unroll
  for (int kh = 0; kh < KH; kh++) {
    // coalesced fragment-order W loads: p = base + lane*8 (L2-hot)
    const ushort_t* wb = Wsw + ((size_t)(wv * KH + kh) * 8) * 2 * 512 + lane * 8;
    bf16x8 wbh[8], wbl[8];
#pragma unroll
    for (int t = 0; t < 8; t++) {
      wbh[t] = *(const bf16x8*)(wb + (size_t)t * 1024);
      wbl[t] = *(const bf16x8*)(wb + (size_t)t * 1024 + 512);
    }
#pragma unroll
    for (int t = 0; t < 8; t++) {
      int ko = kh * 128 + t * 16 + fq * 8;
      bf16x8 ah = *(const bf16x8*)&xh_lds[fm * XS + ko];
      bf16x8 al = *(const bf16x8*)&xl_lds[fm * XS + ko];
      acc = __builtin_amdgcn_mfma_f32_32x32x16_bf16(ah, wbh[t], acc, 0, 0, 0);
      acc = __builtin_amdgcn_mfma_f32_32x32x16_bf16(ah, wbl[t], acc, 0, 0, 0);
      acc = __builtin_amdgcn_mfma_f32_32x32x16_bf16(al, wbh[t], acc, 0, 0, 0);
    }
  }
  // epilogue: C/D col=lane&31, row=(r&3)+8*(r>>2)+4*fq
  int j = wv * 32 + fm;
  float bv = HAS_BIAS ? bias[j] : 0.f;
#pragma unroll
  for (int r = 0; r < 16; r++) {
    int row = (r & 3) + 8 * (r >> 2) + 4 * fq;
    int node = node0 + row;
    if (node < N_NODES)
      OutT[(size_t)node * D + j] = f2bf((acc[r] + bv) * dinvp[node]);
  }
}

// ---------------- aggregation ----------------
// T pre-scaled by dinv: out[d] = dinv[d]*(T[d] + sum_{s->d} T[s]) + b.
template <bool RELU, bool SPLIT_OUT>
__global__ __launch_bounds__(256) void k_aggregate(
    const ushort_t* __restrict__ t, const int* __restrict__ row_start,
    const int* __restrict__ csr, const float* __restrict__ dinv,
    const float* __restrict__ bias, float* __restrict__ out_f,
    ushort_t* __restrict__ outH, ushort_t* __restrict__ outL) {
  int wave = threadIdx.x >> 6;
  int lane = threadIdx.x & 63;
  int node = blockIdx.x * 4 + wave;
  if (node >= N_NODES) return;
  const unsigned int* tu = (const unsigned int*)t;
  float ax, ay;
  {
    unsigned int u = tu[(size_t)node * 64 + lane];  // self-loop (pre-scaled)
    ax = bf2f((ushort_t)(u & 0xFFFF));
    ay = bf2f((ushort_t)(u >> 16));
  }
  int e0 = row_start[node], e1 = row_start[node + 1];
  for (int base = e0; base < e1; base += 64) {
    int cnt = min(64, e1 - base);
    int sidx = (lane < cnt) ? csr[base + lane] : 0;
    int i = 0;
    for (; i + 4 <= cnt; i += 4) {
      int s0 = __shfl(sidx, i);
      int s1 = __shfl(sidx, i + 1);
      int s2 = __shfl(sidx, i + 2);
      int s3 = __shfl(sidx, i + 3);
      unsigned int u0 = tu[(size_t)s0 * 64 + lane];
      unsigned int u1 = tu[(size_t)s1 * 64 + lane];
      unsigned int u2 = tu[(size_t)s2 * 64 + lane];
      unsigned int u3 = tu[(size_t)s3 * 64 + lane];
      ax += bf2f((ushort_t)(u0 & 0xFFFF));
      ay += bf2f((ushort_t)(u0 >> 16));
      ax += bf2f((ushort_t)(u1 & 0xFFFF));
      ay += bf2f((ushort_t)(u1 >> 16));
      ax += bf2f((ushort_t)(u2 & 0xFFFF));
      ay += bf2f((ushort_t)(u2 >> 16));
      ax += bf2f((ushort_t)(u3 & 0xFFFF));
      ay += bf2f((ushort_t)(u3 >> 16));
    }
    for (; i < cnt; i++) {
      int s = __shfl(sidx, i);
      unsigned int u = tu[(size_t)s * 64 + lane];
      ax += bf2f((ushort_t)(u & 0xFFFF));
      ay += bf2f((ushort_t)(u >> 16));
    }
  }
  float di = dinv[node];
  ax = di * ax + bias[2 * lane];
  ay = di * ay + bias[2 * lane + 1];
  if (RELU) {
    ax = fmaxf(ax, 0.f);
    ay = fmaxf(ay, 0.f);
  }
  if (SPLIT_OUT) {
    ushort2 h, l;
    h.x = f2bf(ax); l.x = f2bf(ax - bf2f(h.x));
    h.y = f2bf(ay); l.y = f2bf(ay - bf2f(h.y));
    *(ushort2*)&outH[(size_t)node * D + 2 * lane] = h;
    *(ushort2*)&outL[(size_t)node * D + 2 * lane] = l;
  } else {
    float2 o; o.x = ax; o.y = ay;
    *(float2*)&out_f[(size_t)node * D + 2 * lane] = o;
  }
}

extern "C" void kernel_launch(void* const* d_in, const int* in_sizes, int n_in,
                              void* d_out, int out_size, void* d_ws, size_t ws_size,
                              hipStream_t stream) {
  const int* tokens = (const int*)d_in[0];
  const int* edge = (const int*)d_in[1];  // [2][E]
  const void* embed = d_in[2];
  const void* Wn = d_in[3];
  const void* bn = d_in[4];
  const void* w1 = d_in[5];
  const void* b1 = d_in[6];
  const void* w2 = d_in[7];
  const void* b2 = d_in[8];
  float* out = (float*)d_out;  // fp32 output

  const int* src = edge;
  const int* dst = edge + N_EDGES;

  char* ws = (char*)d_ws;
  ushort_t* Xh = (ushort_t*)ws;                    // 12,800,000 B
  ushort_t* Xl = (ushort_t*)(ws + 12800000);       // 12,800,000 B
  ushort_t* T  = (ushort_t*)(ws + 25600000);       // 12,800,000 B
  float* dinv = (float*)(ws + 38400000);           // 200,000 B
  int* row_start = (int*)(ws + 38600064);          // 200,004 B (pad)
  int* degcur = (int*)(ws + 38800128);             // 400,000 B (deg | cursor)
  int* csr = (int*)(ws + 39200128);                // 2,400,000 B
  int* partial = (int*)(ws + 41600192);            // 196 B
  int* flags = (int*)(ws + 41600448);              // 28 B
  ushort_t* WcSw = (ushort_t*)(ws + 41600512);     // 131,072 B (swizzled hi/lo)
  ushort_t* W2Sw = (ushort_t*)(ws + 41731584);     // 65,536 B (swizzled hi/lo)
  float* bias_ws = (float*)(ws + 41797120);        // bc | b1 | b2 (1,536 B)
  float* bcf = bias_ws;
  float* b1f = bias_ws + 128;
  float* b2f = bias_ws + 256;
  int* deg = degcur;
  int* cursor = degcur + N_NODES;

  const int GGRID = (N_NODES + 31) / 32;  // 1563

  // --- dtype detect; fused W precompute (swizzled); w2 swizzle; biases ---
  k_detect<<<1, 256, 0, stream>>>(embed, Wn, bn, w1, b1, w2, b2, flags);
  k_split<<<(16640 + 255) / 256, 256, 0, stream>>>(w2, b1, b2, flags, W2Sw, b1f, b2f);
  k_wc<<<128, 256, 0, stream>>>(Wn, w1, bn, flags, WcSw, bcf);

  // --- CSR build (hierarchical scan) ---
  hipMemsetAsync(degcur, 0, 2 * N_NODES * sizeof(int), stream);
  k_deg<<<(N_EDGES + 255) / 256, 256, 0, stream>>>(dst, deg);
  k_partial<<<N_CHUNKS, 256, 0, stream>>>(deg, partial);
  k_scan_part<<<1, 64, 0, stream>>>(partial, row_start);
  k_scan_final<<<N_CHUNKS, 256, 0, stream>>>(deg, partial, row_start, dinv);
  k_fill<<<(N_EDGES + 255) / 256, 256, 0, stream>>>(src, dst, row_start, cursor, csr);

  // --- conv1 (fused embed): T = (gather(e) @ Wc^T + bc)*dinv ---
  k_gemm_v4<D_IN, true, true><<<GGRID, 256, 0, stream>>>(
      nullptr, nullptr, embed, tokens, flags, WcSw, bcf, dinv, T);
  k_aggregate<true, true><<<(N_NODES + 3) / 4, 256, 0, stream>>>(
      T, row_start, csr, dinv, b1f, nullptr, Xh, Xl);

  // --- conv2: T = (x1 @ w2^T)*dinv ; aggregate + b2 -> out ---
  k_gemm_v4<D, false, false><<<GGRID, 256, 0, stream>>>(
      Xh, Xl, nullptr, nullptr, nullptr, W2Sw, nullptr, dinv, T);
  k_aggregate<false, false><<<(N_NODES + 3) / 4, 256, 0, stream>>>(
      T, row_start, csr, dinv, b2f, out, nullptr, nullptr);
}

// Round 12
// 308.795 us; speedup vs baseline: 1.4674x; 1.0286x over previous
//
#include <hip/hip_runtime.h>
#include <hip/hip_bf16.h>

#define N_NODES 50000
#define N_EDGES 600000
#define D_IN 256
#define D 128

#define SCAN_CHUNK 1024
#define N_CHUNKS ((N_NODES + SCAN_CHUNK - 1) / SCAN_CHUNK)  // 49

typedef unsigned short ushort_t;
typedef __attribute__((ext_vector_type(8))) short bf16x8;
typedef __attribute__((ext_vector_type(16))) float f32x16;

__device__ __forceinline__ float bf2f(ushort_t u) {
  union { unsigned int i; float f; } v;
  v.i = ((unsigned int)u) << 16;
  return v.f;
}
__device__ __forceinline__ ushort_t f2bf(float f) {
  union { float f; unsigned int i; } v;
  v.f = f;
  unsigned int x = v.i;
  unsigned int r = (x + 0x7FFFu + ((x >> 16) & 1u)) >> 16;  // RNE
  return (ushort_t)r;
}

// Swizzled-W addressing: element (j,k) of [128,KDIM] W, hi/lo split:
//   wv=j>>5, fm=j&31, kh=k>>7, t=(k>>4)&7, fq=(k>>3)&1, c=k&7, lane=fq*32+fm
//   addr = (((wv*(KDIM/128)+kh)*8 + t)*2 + hl)*512 + lane*8 + c   [ushorts]
// -> a wave's fragment load is base + lane*16B, perfectly coalesced.

// ---------------- dtype detection (insurance; expected all-fp32) ----------------
__global__ void k_detect(const void* e, const void* wn, const void* bn,
                         const void* w1, const void* b1, const void* w2,
                         const void* b2, int* flags) {
  const void* ptrs[7] = {e, wn, bn, w1, b1, w2, b2};
  const int ns[7] = {12800000, 32768, 128, 16384, 128, 16384, 128};
  __shared__ int red[256];
  int t = threadIdx.x;
  for (int a = 0; a < 7; a++) {
    int pn = ns[a] < 2048 ? ns[a] : 2048;
    const ushort_t* p = (const ushort_t*)ptrs[a];
    int cnt = 0;
    for (int i = t; i < pn; i += 256) {
      ushort_t u = p[i];
      int ex = (u >> 7) & 0xFF;
      if ((u & 0x7FFF) == 0 || (ex >= 100 && ex <= 130)) cnt++;
    }
    red[t] = cnt;
    __syncthreads();
    for (int off = 128; off > 0; off >>= 1) {
      if (t < off) red[t] += red[t + off];
      __syncthreads();
    }
    if (t == 0) flags[a] = (red[0] * 100 >= pn * 85) ? 1 : 0;
    __syncthreads();
  }
}

// Merged prep: blocks [0,128) compute Wc=w1@Wn row j (swizzled hi/lo) + bc;
// blocks [128,193) swizzle w2 + canonicalize b1/b2.
__global__ __launch_bounds__(256) void k_prep(
    const void* wn, const void* w1, const void* bn,
    const void* w2, const void* b1, const void* b2,
    const int* __restrict__ flags,
    ushort_t* __restrict__ WcSw, float* __restrict__ bc,
    ushort_t* __restrict__ W2Sw, float* __restrict__ b1f,
    float* __restrict__ b2f) {
  int bid = blockIdx.x;
  if (bid < 128) {
    int j = bid;
    int k = threadIdx.x;
    int flWn = flags[1], flW1 = flags[3], flBn = flags[2];
    float acc = 0.f;
    for (int m = 0; m < 128; m++) {
      float a = flW1 ? bf2f(((const ushort_t*)w1)[j * 128 + m])
                     : ((const float*)w1)[j * 128 + m];
      float b = flWn ? bf2f(((const ushort_t*)wn)[m * 256 + k])
                     : ((const float*)wn)[m * 256 + k];
      acc += a * b;
    }
    ushort_t h = f2bf(acc);
    ushort_t l = f2bf(acc - bf2f(h));
    int wv = j >> 5, fm = j & 31;
    int kh = k >> 7, t = (k >> 4) & 7, fq = (k >> 3) & 1, c = k & 7;
    int lane = fq * 32 + fm;
    int base = ((wv * 2 + kh) * 8 + t) * 2 * 512 + lane * 8 + c;  // KH=2
    WcSw[base] = h;
    WcSw[base + 512] = l;
    if (k == 0) {
      float s = 0.f;
      for (int m = 0; m < 128; m++) {
        float a = flW1 ? bf2f(((const ushort_t*)w1)[j * 128 + m])
                       : ((const float*)w1)[j * 128 + m];
        float b = flBn ? bf2f(((const ushort_t*)bn)[m]) : ((const float*)bn)[m];
        s += a * b;
      }
      bc[j] = s;
    }
  } else {
    int i = (bid - 128) * 256 + threadIdx.x;
    if (i >= 16640) return;
    if (i < 16384) {
      int fl = flags[5];
      float v = fl ? bf2f(((const ushort_t*)w2)[i]) : ((const float*)w2)[i];
      ushort_t h = f2bf(v);
      ushort_t l = f2bf(v - bf2f(h));
      int j = i >> 7, k = i & 127;
      int wv = j >> 5, fm = j & 31;
      int t = (k >> 4) & 7, fq = (k >> 3) & 1, c = k & 7;
      int lane = fq * 32 + fm;
      int base = (wv * 8 + t) * 2 * 512 + lane * 8 + c;  // KH=1
      W2Sw[base] = h;
      W2Sw[base + 512] = l;
    } else if (i < 16512) {
      int j = i - 16384;
      b1f[j] = flags[4] ? bf2f(((const ushort_t*)b1)[j]) : ((const float*)b1)[j];
    } else {
      int j = i - 16512;
      b2f[j] = flags[6] ? bf2f(((const ushort_t*)b2)[j]) : ((const float*)b2)[j];
    }
  }
}

// ---------------- CSR build (hierarchical scan) ----------------

__global__ void k_deg(const int* __restrict__ dst, int* __restrict__ deg) {
  int e = blockIdx.x * blockDim.x + threadIdx.x;
  if (e < N_EDGES) atomicAdd(&deg[dst[e]], 1);
}

__global__ void k_partial(const int* __restrict__ deg, int* __restrict__ partial) {
  __shared__ int lds[256];
  int b = blockIdx.x, t = threadIdx.x;
  int base = b * SCAN_CHUNK + t * 4;
  int s = 0;
#pragma unroll
  for (int i = 0; i < 4; i++) {
    int idx = base + i;
    if (idx < N_NODES) s += deg[idx];
  }
  lds[t] = s;
  __syncthreads();
  for (int off = 128; off > 0; off >>= 1) {
    if (t < off) lds[t] += lds[t + off];
    __syncthreads();
  }
  if (t == 0) partial[b] = lds[0];
}

__global__ void k_scan_part(int* __restrict__ partial, int* __restrict__ row_start) {
  if (threadIdx.x == 0) {
    int run = 0;
    for (int i = 0; i < N_CHUNKS; i++) {
      int v = partial[i];
      partial[i] = run;
      run += v;
    }
    row_start[N_NODES] = run;  // == N_EDGES
  }
}

__global__ void k_scan_final(const int* __restrict__ deg, const int* __restrict__ partial,
                             int* __restrict__ row_start, float* __restrict__ dinv) {
  __shared__ int lds[256];
  int b = blockIdx.x, t = threadIdx.x;
  int base = b * SCAN_CHUNK + t * 4;
  int v[4];
  int s = 0;
#pragma unroll
  for (int i = 0; i < 4; i++) {
    int idx = base + i;
    v[i] = (idx < N_NODES) ? deg[idx] : 0;
    s += v[i];
  }
  lds[t] = s;
  __syncthreads();
  for (int off = 1; off < 256; off <<= 1) {
    int add = (t >= off) ? lds[t - off] : 0;
    __syncthreads();
    lds[t] += add;
    __syncthreads();
  }
  int excl = lds[t] - s + partial[b];
#pragma unroll
  for (int i = 0; i < 4; i++) {
    int idx = base + i;
    if (idx < N_NODES) {
      row_start[idx] = excl;
      dinv[idx] = rsqrtf((float)(v[i] + 1));  // +1 self-loop
      excl += v[i];
    }
  }
}

__global__ void k_fill(const int* __restrict__ src, const int* __restrict__ dst,
                       const int* __restrict__ row_start, int* __restrict__ cursor,
                       int* __restrict__ csr) {
  int e = blockIdx.x * blockDim.x + threadIdx.x;
  if (e < N_EDGES) {
    int d = dst[e];
    int pos = atomicAdd(&cursor[d], 1);
    csr[row_start[d] + pos] = src[e];
  }
}

// ---------------- MFMA split-bf16 GEMM v4 (swizzled W; conv1 gather) ----------
// T[n][j] = (sum_k X[n][k] W[j][k] + bias[j]) * dinv[n], bf16 out.
template <int KDIM>
__global__ __launch_bounds__(256) void k_gemm_v4(
    const void* __restrict__ Xv, const int* __restrict__ tokens,
    const int* __restrict__ flags,
    const ushort_t* __restrict__ Wsw,
    const float* __restrict__ bias, const float* __restrict__ dinvp,
    ushort_t* __restrict__ OutT) {
  constexpr int KH = KDIM / 128;
  constexpr int XS = KDIM + 8;
  __shared__ __align__(16) ushort_t xh_lds[32 * XS];
  __shared__ __align__(16) ushort_t xl_lds[32 * XS];

  int tid = threadIdx.x;
  int lane = tid & 63;
  int wv = tid >> 6;
  int node0 = blockIdx.x * 32;
  int fm = lane & 31;
  int fq = lane >> 5;

  // ---- stage full-K gathered X tile ----
  {
    constexpr int NT = (32 * KDIM / 4) / 256;
    int fl = flags[0];
    if (fl) {  // bf16 table: hi = value, lo = 0 (exact)
      ushort4 v[NT];
      int rows[NT], cs[NT];
#pragma unroll
      for (int i = 0; i < NT; i++) {
        int seg = tid + 256 * i;
        rows[i] = seg / (KDIM / 4);
        cs[i] = seg % (KDIM / 4);
        int tk = tokens[min(node0 + rows[i], N_NODES - 1)];
        v[i] = *(const ushort4*)&((const ushort_t*)Xv)[(size_t)tk * KDIM + 4 * cs[i]];
      }
      ushort4 z; z.x = 0; z.y = 0; z.z = 0; z.w = 0;
#pragma unroll
      for (int i = 0; i < NT; i++) {
        *(ushort4*)&xh_lds[rows[i] * XS + 4 * cs[i]] = v[i];
        *(ushort4*)&xl_lds[rows[i] * XS + 4 * cs[i]] = z;
      }
    } else {  // fp32 table: on-the-fly hi/lo split
      float4 v[NT];
      int rows[NT], cs[NT];
#pragma unroll
      for (int i = 0; i < NT; i++) {
        int seg = tid + 256 * i;
        rows[i] = seg / (KDIM / 4);
        cs[i] = seg % (KDIM / 4);
        int tk = tokens[min(node0 + rows[i], N_NODES - 1)];
        v[i] = *(const float4*)&((const float*)Xv)[(size_t)tk * KDIM + 4 * cs[i]];
      }
#pragma unroll
      for (int i = 0; i < NT; i++) {
        ushort4 h, l;
        h.x = f2bf(v[i].x); l.x = f2bf(v[i].x - bf2f(h.x));
        h.y = f2bf(v[i].y); l.y = f2bf(v[i].y - bf2f(h.y));
        h.z = f2bf(v[i].z); l.z = f2bf(v[i].z - bf2f(h.z));
        h.w = f2bf(v[i].w); l.w = f2bf(v[i].w - bf2f(h.w));
        *(ushort4*)&xh_lds[rows[i] * XS + 4 * cs[i]] = h;
        *(ushort4*)&xl_lds[rows[i] * XS + 4 * cs[i]] = l;
      }
    }
  }
  __syncthreads();

  f32x16 acc;
#pragma unroll
  for (int r = 0; r < 16; r++) acc[r] = 0.f;

#pragma unroll
  for (int kh = 0; kh < KH; kh++) {
    const ushort_t* wb = Wsw + ((size_t)(wv * KH + kh) * 8) * 2 * 512 + lane * 8;
    bf16x8 wbh[8], wbl[8];
#pragma unroll
    for (int t = 0; t < 8; t++) {
      wbh[t] = *(const bf16x8*)(wb + (size_t)t * 1024);
      wbl[t] = *(const bf16x8*)(wb + (size_t)t * 1024 + 512);
    }
#pragma unroll
    for (int t = 0; t < 8; t++) {
      int ko = kh * 128 + t * 16 + fq * 8;
      bf16x8 ah = *(const bf16x8*)&xh_lds[fm * XS + ko];
      bf16x8 al = *(const bf16x8*)&xl_lds[fm * XS + ko];
      acc = __builtin_amdgcn_mfma_f32_32x32x16_bf16(ah, wbh[t], acc, 0, 0, 0);
      acc = __builtin_amdgcn_mfma_f32_32x32x16_bf16(ah, wbl[t], acc, 0, 0, 0);
      acc = __builtin_amdgcn_mfma_f32_32x32x16_bf16(al, wbh[t], acc, 0, 0, 0);
    }
  }
  int j = wv * 32 + fm;
  float bv = bias[j];
#pragma unroll
  for (int r = 0; r < 16; r++) {
    int row = (r & 3) + 8 * (r >> 2) + 4 * fq;
    int node = node0 + row;
    if (node < N_NODES)
      OutT[(size_t)node * D + j] = f2bf((acc[r] + bv) * dinvp[node]);
  }
}

// ---------------- FUSED aggregate1 + conv2-GEMM ----------------
// Per 32-node block: wave wv aggregates nodes [node0+8wv, node0+8wv+8) from T1
// (prescaled by dinv) -> x1 = relu(dinv*sum + b1) -> hi/lo split into LDS X tile;
// one barrier; then swizzled-W MFMA pass emits T2 = (x1 @ w2^T)*dinv. Saves the
// X1 round-trip through HBM entirely (51 MB) vs separate kernels.
__global__ __launch_bounds__(256) void k_agg_gemm(
    const ushort_t* __restrict__ t1, const int* __restrict__ row_start,
    const int* __restrict__ csr, const float* __restrict__ dinv,
    const float* __restrict__ b1f,
    const ushort_t* __restrict__ Wsw, ushort_t* __restrict__ OutT2) {
  constexpr int XS = 136;
  __shared__ __align__(16) ushort_t xh_lds[32 * XS];
  __shared__ __align__(16) ushort_t xl_lds[32 * XS];

  int tid = threadIdx.x;
  int lane = tid & 63;
  int wv = tid >> 6;
  int node0 = blockIdx.x * 32;
  int fm = lane & 31;
  int fq = lane >> 5;

  const unsigned int* tu = (const unsigned int*)t1;
  float bx = b1f[2 * lane];
  float by = b1f[2 * lane + 1];

  // ---- aggregation phase: 8 nodes per wave ----
  for (int rr = 0; rr < 8; rr++) {
    int row = wv * 8 + rr;
    int node = node0 + row;
    float ax = 0.f, ay = 0.f;
    if (node < N_NODES) {
      unsigned int u = tu[(size_t)node * 64 + lane];  // self-loop (prescaled)
      ax = bf2f((ushort_t)(u & 0xFFFF));
      ay = bf2f((ushort_t)(u >> 16));
      int e0 = row_start[node], e1 = row_start[node + 1];
      for (int base = e0; base < e1; base += 64) {
        int cnt = min(64, e1 - base);
        int sidx = (lane < cnt) ? csr[base + lane] : 0;
        int i = 0;
        for (; i + 4 <= cnt; i += 4) {
          int s0 = __shfl(sidx, i);
          int s1 = __shfl(sidx, i + 1);
          int s2 = __shfl(sidx, i + 2);
          int s3 = __shfl(sidx, i + 3);
          unsigned int u0 = tu[(size_t)s0 * 64 + lane];
          unsigned int u1 = tu[(size_t)s1 * 64 + lane];
          unsigned int u2 = tu[(size_t)s2 * 64 + lane];
          unsigned int u3 = tu[(size_t)s3 * 64 + lane];
          ax += bf2f((ushort_t)(u0 & 0xFFFF));
          ay += bf2f((ushort_t)(u0 >> 16));
          ax += bf2f((ushort_t)(u1 & 0xFFFF));
          ay += bf2f((ushort_t)(u1 >> 16));
          ax += bf2f((ushort_t)(u2 & 0xFFFF));
          ay += bf2f((ushort_t)(u2 >> 16));
          ax += bf2f((ushort_t)(u3 & 0xFFFF));
          ay += bf2f((ushort_t)(u3 >> 16));
        }
        for (; i < cnt; i++) {
          int s = __shfl(sidx, i);
          unsigned int u = tu[(size_t)s * 64 + lane];
          ax += bf2f((ushort_t)(u & 0xFFFF));
          ay += bf2f((ushort_t)(u >> 16));
        }
      }
      float di = dinv[node];
      ax = fmaxf(di * ax + bx, 0.f);
      ay = fmaxf(di * ay + by, 0.f);
    }
    ushort2 h, l;
    h.x = f2bf(ax); l.x = f2bf(ax - bf2f(h.x));
    h.y = f2bf(ay); l.y = f2bf(ay - bf2f(h.y));
    *(ushort2*)&xh_lds[row * XS + 2 * lane] = h;
    *(ushort2*)&xl_lds[row * XS + 2 * lane] = l;
  }
  __syncthreads();

  // ---- GEMM phase (KDIM=128) ----
  f32x16 acc;
#pragma unroll
  for (int r = 0; r < 16; r++) acc[r] = 0.f;
  {
    const ushort_t* wb = Wsw + ((size_t)wv * 8) * 2 * 512 + lane * 8;
    bf16x8 wbh[8], wbl[8];
#pragma unroll
    for (int t = 0; t < 8; t++) {
      wbh[t] = *(const bf16x8*)(wb + (size_t)t * 1024);
      wbl[t] = *(const bf16x8*)(wb + (size_t)t * 1024 + 512);
    }
#pragma unroll
    for (int t = 0; t < 8; t++) {
      int ko = t * 16 + fq * 8;
      bf16x8 ah = *(const bf16x8*)&xh_lds[fm * XS + ko];
      bf16x8 al = *(const bf16x8*)&xl_lds[fm * XS + ko];
      acc = __builtin_amdgcn_mfma_f32_32x32x16_bf16(ah, wbh[t], acc, 0, 0, 0);
      acc = __builtin_amdgcn_mfma_f32_32x32x16_bf16(ah, wbl[t], acc, 0, 0, 0);
      acc = __builtin_amdgcn_mfma_f32_32x32x16_bf16(al, wbh[t], acc, 0, 0, 0);
    }
  }
  int j = wv * 32 + fm;
#pragma unroll
  for (int r = 0; r < 16; r++) {
    int row = (r & 3) + 8 * (r >> 2) + 4 * fq;
    int node = node0 + row;
    if (node < N_NODES)
      OutT2[(size_t)node * D + j] = f2bf(acc[r] * dinv[node]);
  }
}

// ---------------- final aggregation ----------------
// T2 prescaled by dinv: out[d] = dinv[d]*(T2[d] + sum_{s->d} T2[s]) + b2 (fp32).
__global__ __launch_bounds__(256) void k_aggregate_out(
    const ushort_t* __restrict__ t, const int* __restrict__ row_start,
    const int* __restrict__ csr, const float* __restrict__ dinv,
    const float* __restrict__ bias, float* __restrict__ out_f) {
  int wave = threadIdx.x >> 6;
  int lane = threadIdx.x & 63;
  int node = blockIdx.x * 4 + wave;
  if (node >= N_NODES) return;
  const unsigned int* tu = (const unsigned int*)t;
  float ax, ay;
  {
    unsigned int u = tu[(size_t)node * 64 + lane];
    ax = bf2f((ushort_t)(u & 0xFFFF));
    ay = bf2f((ushort_t)(u >> 16));
  }
  int e0 = row_start[node], e1 = row_start[node + 1];
  for (int base = e0; base < e1; base += 64) {
    int cnt = min(64, e1 - base);
    int sidx = (lane < cnt) ? csr[base + lane] : 0;
    int i = 0;
    for (; i + 4 <= cnt; i += 4) {
      int s0 = __shfl(sidx, i);
      int s1 = __shfl(sidx, i + 1);
      int s2 = __shfl(sidx, i + 2);
      int s3 = __shfl(sidx, i + 3);
      unsigned int u0 = tu[(size_t)s0 * 64 + lane];
      unsigned int u1 = tu[(size_t)s1 * 64 + lane];
      unsigned int u2 = tu[(size_t)s2 * 64 + lane];
      unsigned int u3 = tu[(size_t)s3 * 64 + lane];
      ax += bf2f((ushort_t)(u0 & 0xFFFF));
      ay += bf2f((ushort_t)(u0 >> 16));
      ax += bf2f((ushort_t)(u1 & 0xFFFF));
      ay += bf2f((ushort_t)(u1 >> 16));
      ax += bf2f((ushort_t)(u2 & 0xFFFF));
      ay += bf2f((ushort_t)(u2 >> 16));
      ax += bf2f((ushort_t)(u3 & 0xFFFF));
      ay += bf2f((ushort_t)(u3 >> 16));
    }
    for (; i < cnt; i++) {
      int s = __shfl(sidx, i);
      unsigned int u = tu[(size_t)s * 64 + lane];
      ax += bf2f((ushort_t)(u & 0xFFFF));
      ay += bf2f((ushort_t)(u >> 16));
    }
  }
  float di = dinv[node];
  ax = di * ax + bias[2 * lane];
  ay = di * ay + bias[2 * lane + 1];
  float2 o; o.x = ax; o.y = ay;
  *(float2*)&out_f[(size_t)node * D + 2 * lane] = o;
}

extern "C" void kernel_launch(void* const* d_in, const int* in_sizes, int n_in,
                              void* d_out, int out_size, void* d_ws, size_t ws_size,
                              hipStream_t stream) {
  const int* tokens = (const int*)d_in[0];
  const int* edge = (const int*)d_in[1];  // [2][E]
  const void* embed = d_in[2];
  const void* Wn = d_in[3];
  const void* bn = d_in[4];
  const void* w1 = d_in[5];
  const void* b1 = d_in[6];
  const void* w2 = d_in[7];
  const void* b2 = d_in[8];
  float* out = (float*)d_out;  // fp32 output

  const int* src = edge;
  const int* dst = edge + N_EDGES;

  char* ws = (char*)d_ws;
  ushort_t* T1 = (ushort_t*)ws;                    // 12,800,000 B
  ushort_t* T2 = (ushort_t*)(ws + 12800000);       // 12,800,000 B
  float* dinv = (float*)(ws + 38400000);           // 200,000 B
  int* row_start = (int*)(ws + 38600064);          // 200,004 B (pad)
  int* degcur = (int*)(ws + 38800128);             // 400,000 B (deg | cursor)
  int* csr = (int*)(ws + 39200128);                // 2,400,000 B
  int* partial = (int*)(ws + 41600192);            // 196 B
  int* flags = (int*)(ws + 41600448);              // 28 B
  ushort_t* WcSw = (ushort_t*)(ws + 41600512);     // 131,072 B (swizzled hi/lo)
  ushort_t* W2Sw = (ushort_t*)(ws + 41731584);     // 65,536 B (swizzled hi/lo)
  float* bias_ws = (float*)(ws + 41797120);        // bc | b1 | b2 (1,536 B)
  float* bcf = bias_ws;
  float* b1f = bias_ws + 128;
  float* b2f = bias_ws + 256;
  int* deg = degcur;
  int* cursor = degcur + N_NODES;

  const int GGRID = (N_NODES + 31) / 32;  // 1563

  // --- dtype detect; merged prep (Wc swizzled + w2 swizzled + biases) ---
  k_detect<<<1, 256, 0, stream>>>(embed, Wn, bn, w1, b1, w2, b2, flags);
  k_prep<<<193, 256, 0, stream>>>(Wn, w1, bn, w2, b1, b2, flags,
                                  WcSw, bcf, W2Sw, b1f, b2f);

  // --- CSR build (hierarchical scan) ---
  hipMemsetAsync(degcur, 0, 2 * N_NODES * sizeof(int), stream);
  k_deg<<<(N_EDGES + 255) / 256, 256, 0, stream>>>(dst, deg);
  k_partial<<<N_CHUNKS, 256, 0, stream>>>(deg, partial);
  k_scan_part<<<1, 64, 0, stream>>>(partial, row_start);
  k_scan_final<<<N_CHUNKS, 256, 0, stream>>>(deg, partial, row_start, dinv);
  k_fill<<<(N_EDGES + 255) / 256, 256, 0, stream>>>(src, dst, row_start, cursor, csr);

  // --- conv1 (fused embed): T1 = (gather(e) @ Wc^T + bc)*dinv ---
  k_gemm_v4<D_IN><<<GGRID, 256, 0, stream>>>(
      embed, tokens, flags, WcSw, bcf, dinv, T1);

  // --- fused: x1 = relu(agg(T1)+b1); T2 = (x1 @ w2^T)*dinv ---
  k_agg_gemm<<<GGRID, 256, 0, stream>>>(
      T1, row_start, csr, dinv, b1f, W2Sw, T2);

  // --- final aggregate + b2 -> out (fp32) ---
  k_aggregate_out<<<(N_NODES + 3) / 4, 256, 0, stream>>>(
      T2, row_start, csr, dinv, b2f, out);
}

// Round 14
// 256.883 us; speedup vs baseline: 1.7640x; 1.2021x over previous
//
#include <hip/hip_runtime.h>
#include <hip/hip_bf16.h>

#define N_NODES 50000
#define N_EDGES 600000
#define D_IN 256
#define D 128

#define SCAN_CHUNK 1024
#define N_CHUNKS ((N_NODES + SCAN_CHUNK - 1) / SCAN_CHUNK)  // 49

typedef unsigned short ushort_t;
typedef __attribute__((ext_vector_type(8))) short bf16x8;
typedef __attribute__((ext_vector_type(16))) float f32x16;

__device__ __forceinline__ float bf2f(ushort_t u) {
  union { unsigned int i; float f; } v;
  v.i = ((unsigned int)u) << 16;
  return v.f;
}
__device__ __forceinline__ ushort_t f2bf(float f) {
  union { float f; unsigned int i; } v;
  v.f = f;
  unsigned int x = v.i;
  unsigned int r = (x + 0x7FFFu + ((x >> 16) & 1u)) >> 16;  // RNE
  return (ushort_t)r;
}

// Swizzled-W addressing: element (j,k) of [128,KDIM] W, hi/lo split:
//   wv=j>>5, fm=j&31, kh=k>>7, t=(k>>4)&7, fq=(k>>3)&1, c=k&7, lane=fq*32+fm
//   addr = (((wv*(KDIM/128)+kh)*8 + t)*2 + hl)*512 + lane*8 + c   [ushorts]
// -> a wave's fragment load is base + lane*16B, perfectly coalesced.

// ---------------- merged prep + degree count ----------------
// blocks [0,128):   Wc = w1 @ Wn row j (swizzled hi/lo) + bc = w1 @ bn
// blocks [128,193): swizzle w2 hi/lo + canonicalize b1/b2
// blocks [193,...): degree count over edges
__global__ __launch_bounds__(256) void k_prep_deg(
    const float* __restrict__ wn, const float* __restrict__ w1,
    const float* __restrict__ bn, const float* __restrict__ w2,
    const float* __restrict__ b1, const float* __restrict__ b2,
    const int* __restrict__ dst,
    ushort_t* __restrict__ WcSw, float* __restrict__ bc,
    ushort_t* __restrict__ W2Sw, float* __restrict__ b1f,
    float* __restrict__ b2f, int* __restrict__ deg) {
  int bid = blockIdx.x;
  if (bid < 128) {
    int j = bid;
    int k = threadIdx.x;
    float acc = 0.f;
    for (int m = 0; m < 128; m++)
      acc += w1[j * 128 + m] * wn[m * 256 + k];
    ushort_t h = f2bf(acc);
    ushort_t l = f2bf(acc - bf2f(h));
    int wv = j >> 5, fm = j & 31;
    int kh = k >> 7, t = (k >> 4) & 7, fq = (k >> 3) & 1, c = k & 7;
    int lane = fq * 32 + fm;
    int base = ((wv * 2 + kh) * 8 + t) * 2 * 512 + lane * 8 + c;  // KH=2
    WcSw[base] = h;
    WcSw[base + 512] = l;
    if (k == 0) {
      float s = 0.f;
      for (int m = 0; m < 128; m++) s += w1[j * 128 + m] * bn[m];
      bc[j] = s;
    }
  } else if (bid < 193) {
    int i = (bid - 128) * 256 + threadIdx.x;
    if (i >= 16640) return;
    if (i < 16384) {
      float v = w2[i];
      ushort_t h = f2bf(v);
      ushort_t l = f2bf(v - bf2f(h));
      int j = i >> 7, k = i & 127;
      int wv = j >> 5, fm = j & 31;
      int t = (k >> 4) & 7, fq = (k >> 3) & 1, c = k & 7;
      int lane = fq * 32 + fm;
      int base = (wv * 8 + t) * 2 * 512 + lane * 8 + c;  // KH=1
      W2Sw[base] = h;
      W2Sw[base + 512] = l;
    } else if (i < 16512) {
      b1f[i - 16384] = b1[i - 16384];
    } else {
      b2f[i - 16512] = b2[i - 16512];
    }
  } else {
    int e = (bid - 193) * 256 + threadIdx.x;
    if (e < N_EDGES) atomicAdd(&deg[dst[e]], 1);
  }
}

// ---------------- CSR scan (partial sums, then final incl. partial-prefix) ----

__global__ void k_partial(const int* __restrict__ deg, int* __restrict__ partial) {
  __shared__ int lds[256];
  int b = blockIdx.x, t = threadIdx.x;
  int base = b * SCAN_CHUNK + t * 4;
  int s = 0;
#pragma unroll
  for (int i = 0; i < 4; i++) {
    int idx = base + i;
    if (idx < N_NODES) s += deg[idx];
  }
  lds[t] = s;
  __syncthreads();
  for (int off = 128; off > 0; off >>= 1) {
    if (t < off) lds[t] += lds[t + off];
    __syncthreads();
  }
  if (t == 0) partial[b] = lds[0];
}

__global__ void k_scan_final(const int* __restrict__ deg, const int* __restrict__ partial,
                             int* __restrict__ row_start, float* __restrict__ dinv) {
  __shared__ int lds[256];
  __shared__ int plds[64];
  int b = blockIdx.x, t = threadIdx.x;
  if (t < N_CHUNKS) plds[t] = partial[t];
  __syncthreads();
  if (t == 0) {
    int s = 0;
    for (int i = 0; i < b; i++) s += plds[i];
    plds[63] = s;  // prefix of partials before this block (N_CHUNKS=49 < 63)
  }
  int base = b * SCAN_CHUNK + t * 4;
  int v[4];
  int s = 0;
#pragma unroll
  for (int i = 0; i < 4; i++) {
    int idx = base + i;
    v[i] = (idx < N_NODES) ? deg[idx] : 0;
    s += v[i];
  }
  lds[t] = s;
  __syncthreads();
  for (int off = 1; off < 256; off <<= 1) {
    int add = (t >= off) ? lds[t - off] : 0;
    __syncthreads();
    lds[t] += add;
    __syncthreads();
  }
  int excl = lds[t] - s + plds[63];
#pragma unroll
  for (int i = 0; i < 4; i++) {
    int idx = base + i;
    if (idx < N_NODES) {
      row_start[idx] = excl;
      dinv[idx] = rsqrtf((float)(v[i] + 1));  // +1 self-loop
      excl += v[i];
    }
  }
  if (b == 0 && t == 0) row_start[N_NODES] = N_EDGES;
}

__global__ void k_fill(const int* __restrict__ src, const int* __restrict__ dst,
                       const int* __restrict__ row_start, int* __restrict__ cursor,
                       int* __restrict__ csr) {
  int e = blockIdx.x * blockDim.x + threadIdx.x;
  if (e < N_EDGES) {
    int d = dst[e];
    int pos = atomicAdd(&cursor[d], 1);
    csr[row_start[d] + pos] = src[e];
  }
}

// ---------------- MFMA split-bf16 GEMM (swizzled W; conv1 embed gather) ------
// T[n][j] = (sum_k X[n][k] W[j][k] + bias[j]) * dinv[n], bf16 out. KDIM=256.
__global__ __launch_bounds__(256) void k_gemm_v4(
    const float* __restrict__ Xv, const int* __restrict__ tokens,
    const ushort_t* __restrict__ Wsw,
    const float* __restrict__ bias, const float* __restrict__ dinvp,
    ushort_t* __restrict__ OutT) {
  constexpr int KDIM = D_IN;
  constexpr int KH = KDIM / 128;
  constexpr int XS = KDIM + 8;
  __shared__ __align__(16) ushort_t xh_lds[32 * XS];
  __shared__ __align__(16) ushort_t xl_lds[32 * XS];

  int tid = threadIdx.x;
  int lane = tid & 63;
  int wv = tid >> 6;
  int node0 = blockIdx.x * 32;
  int fm = lane & 31;
  int fq = lane >> 5;

  // ---- stage full-K gathered X tile (fp32 table, on-the-fly hi/lo split) ----
  {
    constexpr int NT = (32 * KDIM / 4) / 256;  // 8
    float4 v[NT];
    int rows[NT], cs[NT];
#pragma unroll
    for (int i = 0; i < NT; i++) {
      int seg = tid + 256 * i;
      rows[i] = seg / (KDIM / 4);
      cs[i] = seg % (KDIM / 4);
      int tk = tokens[min(node0 + rows[i], N_NODES - 1)];
      v[i] = *(const float4*)&Xv[(size_t)tk * KDIM + 4 * cs[i]];
    }
#pragma unroll
    for (int i = 0; i < NT; i++) {
      ushort4 h, l;
      h.x = f2bf(v[i].x); l.x = f2bf(v[i].x - bf2f(h.x));
      h.y = f2bf(v[i].y); l.y = f2bf(v[i].y - bf2f(h.y));
      h.z = f2bf(v[i].z); l.z = f2bf(v[i].z - bf2f(h.z));
      h.w = f2bf(v[i].w); l.w = f2bf(v[i].w - bf2f(h.w));
      *(ushort4*)&xh_lds[rows[i] * XS + 4 * cs[i]] = h;
      *(ushort4*)&xl_lds[rows[i] * XS + 4 * cs[i]] = l;
    }
  }
  __syncthreads();

  f32x16 acc;
#pragma unroll
  for (int r = 0; r < 16; r++) acc[r] = 0.f;

#pragma unroll
  for (int kh = 0; kh < KH; kh++) {
    const ushort_t* wb = Wsw + ((size_t)(wv * KH + kh) * 8) * 2 * 512 + lane * 8;
    bf16x8 wbh[8], wbl[8];
#pragma unroll
    for (int t = 0; t < 8; t++) {
      wbh[t] = *(const bf16x8*)(wb + (size_t)t * 1024);
      wbl[t] = *(const bf16x8*)(wb + (size_t)t * 1024 + 512);
    }
#pragma unroll
    for (int t = 0; t < 8; t++) {
      int ko = kh * 128 + t * 16 + fq * 8;
      bf16x8 ah = *(const bf16x8*)&xh_lds[fm * XS + ko];
      bf16x8 al = *(const bf16x8*)&xl_lds[fm * XS + ko];
      acc = __builtin_amdgcn_mfma_f32_32x32x16_bf16(ah, wbh[t], acc, 0, 0, 0);
      acc = __builtin_amdgcn_mfma_f32_32x32x16_bf16(ah, wbl[t], acc, 0, 0, 0);
      acc = __builtin_amdgcn_mfma_f32_32x32x16_bf16(al, wbh[t], acc, 0, 0, 0);
    }
  }
  int j = wv * 32 + fm;
  float bv = bias[j];
#pragma unroll
  for (int r = 0; r < 16; r++) {
    int row = (r & 3) + 8 * (r >> 2) + 4 * fq;
    int node = node0 + row;
    if (node < N_NODES)
      OutT[(size_t)node * D + j] = f2bf((acc[r] + bv) * dinvp[node]);
  }
}

// Edge-gather accumulate helper: unroll 8 outstanding row loads.
__device__ __forceinline__ void agg_edges(
    const unsigned int* __restrict__ tu, const int* __restrict__ csr,
    int e0, int e1, int lane, float& ax, float& ay) {
  for (int base = e0; base < e1; base += 64) {
    int cnt = min(64, e1 - base);
    int sidx = (lane < cnt) ? csr[base + lane] : 0;
    int i = 0;
    for (; i + 8 <= cnt; i += 8) {
      unsigned int u[8];
#pragma unroll
      for (int q = 0; q < 8; q++) {
        int s = __shfl(sidx, i + q);
        u[q] = tu[(size_t)s * 64 + lane];
      }
#pragma unroll
      for (int q = 0; q < 8; q++) {
        ax += bf2f((ushort_t)(u[q] & 0xFFFF));
        ay += bf2f((ushort_t)(u[q] >> 16));
      }
    }
    for (; i + 4 <= cnt; i += 4) {
      unsigned int u[4];
#pragma unroll
      for (int q = 0; q < 4; q++) {
        int s = __shfl(sidx, i + q);
        u[q] = tu[(size_t)s * 64 + lane];
      }
#pragma unroll
      for (int q = 0; q < 4; q++) {
        ax += bf2f((ushort_t)(u[q] & 0xFFFF));
        ay += bf2f((ushort_t)(u[q] >> 16));
      }
    }
    for (; i < cnt; i++) {
      int s = __shfl(sidx, i);
      unsigned int u = tu[(size_t)s * 64 + lane];
      ax += bf2f((ushort_t)(u & 0xFFFF));
      ay += bf2f((ushort_t)(u >> 16));
    }
  }
}

// ---------------- FUSED aggregate1 + conv2-GEMM ----------------
// Wave wv aggregates nodes [node0+8wv, +8) from T1 (prescaled) -> x1 =
// relu(dinv*sum + b1) -> hi/lo split into LDS; one barrier; swizzled-W MFMA
// emits T2 = (x1 @ w2^T)*dinv.
__global__ __launch_bounds__(256) void k_agg_gemm(
    const ushort_t* __restrict__ t1, const int* __restrict__ row_start,
    const int* __restrict__ csr, const float* __restrict__ dinv,
    const float* __restrict__ b1f,
    const ushort_t* __restrict__ Wsw, ushort_t* __restrict__ OutT2) {
  constexpr int XS = 136;
  __shared__ __align__(16) ushort_t xh_lds[32 * XS];
  __shared__ __align__(16) ushort_t xl_lds[32 * XS];

  int tid = threadIdx.x;
  int lane = tid & 63;
  int wv = tid >> 6;
  int node0 = blockIdx.x * 32;
  int fm = lane & 31;
  int fq = lane >> 5;

  const unsigned int* tu = (const unsigned int*)t1;
  float bx = b1f[2 * lane];
  float by = b1f[2 * lane + 1];

  for (int rr = 0; rr < 8; rr++) {
    int row = wv * 8 + rr;
    int node = node0 + row;
    float ax = 0.f, ay = 0.f;
    if (node < N_NODES) {
      unsigned int u = tu[(size_t)node * 64 + lane];  // self-loop (prescaled)
      ax = bf2f((ushort_t)(u & 0xFFFF));
      ay = bf2f((ushort_t)(u >> 16));
      agg_edges(tu, csr, row_start[node], row_start[node + 1], lane, ax, ay);
      float di = dinv[node];
      ax = fmaxf(di * ax + bx, 0.f);
      ay = fmaxf(di * ay + by, 0.f);
    }
    ushort2 h, l;
    h.x = f2bf(ax); l.x = f2bf(ax - bf2f(h.x));
    h.y = f2bf(ay); l.y = f2bf(ay - bf2f(h.y));
    *(ushort2*)&xh_lds[row * XS + 2 * lane] = h;
    *(ushort2*)&xl_lds[row * XS + 2 * lane] = l;
  }
  __syncthreads();

  f32x16 acc;
#pragma unroll
  for (int r = 0; r < 16; r++) acc[r] = 0.f;
  {
    const ushort_t* wb = Wsw + ((size_t)wv * 8) * 2 * 512 + lane * 8;
    bf16x8 wbh[8], wbl[8];
#pragma unroll
    for (int t = 0; t < 8; t++) {
      wbh[t] = *(const bf16x8*)(wb + (size_t)t * 1024);
      wbl[t] = *(const bf16x8*)(wb + (size_t)t * 1024 + 512);
    }
#pragma unroll
    for (int t = 0; t < 8; t++) {
      int ko = t * 16 + fq * 8;
      bf16x8 ah = *(const bf16x8*)&xh_lds[fm * XS + ko];
      bf16x8 al = *(const bf16x8*)&xl_lds[fm * XS + ko];
      acc = __builtin_amdgcn_mfma_f32_32x32x16_bf16(ah, wbh[t], acc, 0, 0, 0);
      acc = __builtin_amdgcn_mfma_f32_32x32x16_bf16(ah, wbl[t], acc, 0, 0, 0);
      acc = __builtin_amdgcn_mfma_f32_32x32x16_bf16(al, wbh[t], acc, 0, 0, 0);
    }
  }
  int j = wv * 32 + fm;
#pragma unroll
  for (int r = 0; r < 16; r++) {
    int row = (r & 3) + 8 * (r >> 2) + 4 * fq;
    int node = node0 + row;
    if (node < N_NODES)
      OutT2[(size_t)node * D + j] = f2bf(acc[r] * dinv[node]);
  }
}

// ---------------- final aggregation -> fp32 out ----------------
__global__ __launch_bounds__(256) void k_aggregate_out(
    const ushort_t* __restrict__ t, const int* __restrict__ row_start,
    const int* __restrict__ csr, const float* __restrict__ dinv,
    const float* __restrict__ bias, float* __restrict__ out_f) {
  int wave = threadIdx.x >> 6;
  int lane = threadIdx.x & 63;
  int node = blockIdx.x * 4 + wave;
  if (node >= N_NODES) return;
  const unsigned int* tu = (const unsigned int*)t;
  float ax, ay;
  {
    unsigned int u = tu[(size_t)node * 64 + lane];
    ax = bf2f((ushort_t)(u & 0xFFFF));
    ay = bf2f((ushort_t)(u >> 16));
  }
  agg_edges(tu, csr, row_start[node], row_start[node + 1], lane, ax, ay);
  float di = dinv[node];
  ax = di * ax + bias[2 * lane];
  ay = di * ay + bias[2 * lane + 1];
  float2 o; o.x = ax; o.y = ay;
  *(float2*)&out_f[(size_t)node * D + 2 * lane] = o;
}

extern "C" void kernel_launch(void* const* d_in, const int* in_sizes, int n_in,
                              void* d_out, int out_size, void* d_ws, size_t ws_size,
                              hipStream_t stream) {
  const int* tokens = (const int*)d_in[0];
  const int* edge = (const int*)d_in[1];  // [2][E]
  const float* embed = (const float*)d_in[2];
  const float* Wn = (const float*)d_in[3];
  const float* bn = (const float*)d_in[4];
  const float* w1 = (const float*)d_in[5];
  const float* b1 = (const float*)d_in[6];
  const float* w2 = (const float*)d_in[7];
  const float* b2 = (const float*)d_in[8];
  float* out = (float*)d_out;  // fp32 output

  const int* src = edge;
  const int* dst = edge + N_EDGES;

  char* ws = (char*)d_ws;
  ushort_t* T1 = (ushort_t*)ws;                    // 12,800,000 B
  ushort_t* T2 = (ushort_t*)(ws + 12800000);       // 12,800,000 B
  float* dinv = (float*)(ws + 38400000);           // 200,000 B
  int* row_start = (int*)(ws + 38600064);          // 200,004 B (pad)
  int* degcur = (int*)(ws + 38800128);             // 400,000 B (deg | cursor)
  int* csr = (int*)(ws + 39200128);                // 2,400,000 B
  int* partial = (int*)(ws + 41600192);            // 196 B
  ushort_t* WcSw = (ushort_t*)(ws + 41600512);     // 131,072 B (swizzled hi/lo)
  ushort_t* W2Sw = (ushort_t*)(ws + 41731584);     // 65,536 B (swizzled hi/lo)
  float* bias_ws = (float*)(ws + 41797120);        // bc | b1 | b2 (1,536 B)
  float* bcf = bias_ws;
  float* b1f = bias_ws + 128;
  float* b2f = bias_ws + 256;
  int* deg = degcur;
  int* cursor = degcur + N_NODES;

  const int GGRID = (N_NODES + 31) / 32;  // 1563
  const int DEG_BLOCKS = (N_EDGES + 255) / 256;  // 2344

  // --- zero deg+cursor; merged prep (Wc, w2 swizzle, biases) + degree count ---
  hipMemsetAsync(degcur, 0, 2 * N_NODES * sizeof(int), stream);
  k_prep_deg<<<193 + DEG_BLOCKS, 256, 0, stream>>>(
      Wn, w1, bn, w2, b1, b2, dst, WcSw, bcf, W2Sw, b1f, b2f, deg);

  // --- CSR scan + fill ---
  k_partial<<<N_CHUNKS, 256, 0, stream>>>(deg, partial);
  k_scan_final<<<N_CHUNKS, 256, 0, stream>>>(deg, partial, row_start, dinv);
  k_fill<<<DEG_BLOCKS, 256, 0, stream>>>(src, dst, row_start, cursor, csr);

  // --- conv1 (fused embed): T1 = (gather(e) @ Wc^T + bc)*dinv ---
  k_gemm_v4<<<GGRID, 256, 0, stream>>>(embed, tokens, WcSw, bcf, dinv, T1);

  // --- fused: x1 = relu(agg(T1)+b1); T2 = (x1 @ w2^T)*dinv ---
  k_agg_gemm<<<GGRID, 256, 0, stream>>>(
      T1, row_start, csr, dinv, b1f, W2Sw, T2);

  // --- final aggregate + b2 -> out (fp32) ---
  k_aggregate_out<<<(N_NODES + 3) / 4, 256, 0, stream>>>(
      T2, row_start, csr, dinv, b2f, out);
}

// Round 15
// 245.559 us; speedup vs baseline: 1.8453x; 1.0461x over previous
//
#include <hip/hip_runtime.h>
#include <hip/hip_bf16.h>

#define N_NODES 50000
#define N_EDGES 600000
#define D_IN 256
#define D 128

#define SCAN_CHUNK 1024
#define N_CHUNKS ((N_NODES + SCAN_CHUNK - 1) / SCAN_CHUNK)  // 49
#define GEMM_BLOCKS ((N_NODES + 31) / 32)                   // 1563
#define EDGE_BLOCKS ((N_EDGES + 255) / 256)                 // 2344

typedef unsigned short ushort_t;
typedef __attribute__((ext_vector_type(8))) short bf16x8;
typedef __attribute__((ext_vector_type(16))) float f32x16;

__device__ __forceinline__ float bf2f(ushort_t u) {
  union { unsigned int i; float f; } v;
  v.i = ((unsigned int)u) << 16;
  return v.f;
}
__device__ __forceinline__ ushort_t f2bf(float f) {
  union { float f; unsigned int i; } v;
  v.f = f;
  unsigned int x = v.i;
  unsigned int r = (x + 0x7FFFu + ((x >> 16) & 1u)) >> 16;  // RNE
  return (ushort_t)r;
}

// Swizzled-W addressing: element (j,k) of [128,KDIM] W, hi/lo split:
//   wv=j>>5, fm=j&31, kh=k>>7, t=(k>>4)&7, fq=(k>>3)&1, c=k&7, lane=fq*32+fm
//   addr = (((wv*(KDIM/128)+kh)*8 + t)*2 + hl)*512 + lane*8 + c   [ushorts]
// -> a wave's fragment load is base + lane*16B, perfectly coalesced.

// ---------------- merged prep + degree count ----------------
__global__ __launch_bounds__(256) void k_prep_deg(
    const float* __restrict__ wn, const float* __restrict__ w1,
    const float* __restrict__ bn, const float* __restrict__ w2,
    const float* __restrict__ b1, const float* __restrict__ b2,
    const int* __restrict__ dst,
    ushort_t* __restrict__ WcSw, float* __restrict__ bc,
    ushort_t* __restrict__ W2Sw, float* __restrict__ b1f,
    float* __restrict__ b2f, int* __restrict__ deg) {
  int bid = blockIdx.x;
  if (bid < 128) {
    int j = bid;
    int k = threadIdx.x;
    float acc = 0.f;
    for (int m = 0; m < 128; m++)
      acc += w1[j * 128 + m] * wn[m * 256 + k];
    ushort_t h = f2bf(acc);
    ushort_t l = f2bf(acc - bf2f(h));
    int wv = j >> 5, fm = j & 31;
    int kh = k >> 7, t = (k >> 4) & 7, fq = (k >> 3) & 1, c = k & 7;
    int lane = fq * 32 + fm;
    int base = ((wv * 2 + kh) * 8 + t) * 2 * 512 + lane * 8 + c;  // KH=2
    WcSw[base] = h;
    WcSw[base + 512] = l;
    if (k == 0) {
      float s = 0.f;
      for (int m = 0; m < 128; m++) s += w1[j * 128 + m] * bn[m];
      bc[j] = s;
    }
  } else if (bid < 193) {
    int i = (bid - 128) * 256 + threadIdx.x;
    if (i >= 16640) return;
    if (i < 16384) {
      float v = w2[i];
      ushort_t h = f2bf(v);
      ushort_t l = f2bf(v - bf2f(h));
      int j = i >> 7, k = i & 127;
      int wv = j >> 5, fm = j & 31;
      int t = (k >> 4) & 7, fq = (k >> 3) & 1, c = k & 7;
      int lane = fq * 32 + fm;
      int base = (wv * 8 + t) * 2 * 512 + lane * 8 + c;  // KH=1
      W2Sw[base] = h;
      W2Sw[base + 512] = l;
    } else if (i < 16512) {
      b1f[i - 16384] = b1[i - 16384];
    } else {
      b2f[i - 16512] = b2[i - 16512];
    }
  } else {
    int e = (bid - 193) * 256 + threadIdx.x;
    if (e < N_EDGES) atomicAdd(&deg[dst[e]], 1);
  }
}

// ---------------- CSR scan ----------------

__global__ void k_partial(const int* __restrict__ deg, int* __restrict__ partial) {
  __shared__ int lds[256];
  int b = blockIdx.x, t = threadIdx.x;
  int base = b * SCAN_CHUNK + t * 4;
  int s = 0;
#pragma unroll
  for (int i = 0; i < 4; i++) {
    int idx = base + i;
    if (idx < N_NODES) s += deg[idx];
  }
  lds[t] = s;
  __syncthreads();
  for (int off = 128; off > 0; off >>= 1) {
    if (t < off) lds[t] += lds[t + off];
    __syncthreads();
  }
  if (t == 0) partial[b] = lds[0];
}

// Also zeroes cursor[] (saves half the memset).
__global__ void k_scan_final(const int* __restrict__ deg, const int* __restrict__ partial,
                             int* __restrict__ row_start, float* __restrict__ dinv,
                             int* __restrict__ cursor) {
  __shared__ int lds[256];
  __shared__ int plds[64];
  int b = blockIdx.x, t = threadIdx.x;
  if (t < N_CHUNKS) plds[t] = partial[t];
  __syncthreads();
  if (t == 0) {
    int s = 0;
    for (int i = 0; i < b; i++) s += plds[i];
    plds[63] = s;  // prefix of partials before this block (N_CHUNKS=49 < 63)
  }
  int base = b * SCAN_CHUNK + t * 4;
  int v[4];
  int s = 0;
#pragma unroll
  for (int i = 0; i < 4; i++) {
    int idx = base + i;
    v[i] = (idx < N_NODES) ? deg[idx] : 0;
    s += v[i];
  }
  lds[t] = s;
  __syncthreads();
  for (int off = 1; off < 256; off <<= 1) {
    int add = (t >= off) ? lds[t - off] : 0;
    __syncthreads();
    lds[t] += add;
    __syncthreads();
  }
  int excl = lds[t] - s + plds[63];
#pragma unroll
  for (int i = 0; i < 4; i++) {
    int idx = base + i;
    if (idx < N_NODES) {
      row_start[idx] = excl;
      dinv[idx] = rsqrtf((float)(v[i] + 1));  // +1 self-loop
      cursor[idx] = 0;
      excl += v[i];
    }
  }
  if (b == 0 && t == 0) row_start[N_NODES] = N_EDGES;
}

// ---------------- MERGED conv1-GEMM + CSR-fill ----------------
// blocks [0, GEMM_BLOCKS): T1[n][j] = (gather(e) @ Wc^T + bc)*dinv, bf16.
// blocks [GEMM_BLOCKS, +EDGE_BLOCKS): CSR scatter fill.
// Both depend only on {prep, scan}; merging lets fill's atomics run in the
// GEMM's idle memory slots (complementary pipes).
__global__ __launch_bounds__(256) void k_gemm_fill(
    const float* __restrict__ Xv, const int* __restrict__ tokens,
    const ushort_t* __restrict__ Wsw,
    const float* __restrict__ bias, const float* __restrict__ dinvp,
    ushort_t* __restrict__ OutT,
    const int* __restrict__ src, const int* __restrict__ dst,
    const int* __restrict__ row_start, int* __restrict__ cursor,
    int* __restrict__ csr) {
  constexpr int KDIM = D_IN;
  constexpr int KH = KDIM / 128;
  constexpr int XS = KDIM + 8;
  __shared__ __align__(16) ushort_t xh_lds[32 * XS];
  __shared__ __align__(16) ushort_t xl_lds[32 * XS];

  int bid = blockIdx.x;
  if (bid >= GEMM_BLOCKS) {
    // ---- CSR fill path ----
    int e = (bid - GEMM_BLOCKS) * 256 + threadIdx.x;
    if (e < N_EDGES) {
      int d = dst[e];
      int pos = atomicAdd(&cursor[d], 1);
      csr[row_start[d] + pos] = src[e];
    }
    return;
  }

  // ---- GEMM path ----
  int tid = threadIdx.x;
  int lane = tid & 63;
  int wv = tid >> 6;
  int node0 = bid * 32;
  int fm = lane & 31;
  int fq = lane >> 5;

  {
    constexpr int NT = (32 * KDIM / 4) / 256;  // 8
    float4 v[NT];
    int rows[NT], cs[NT];
#pragma unroll
    for (int i = 0; i < NT; i++) {
      int seg = tid + 256 * i;
      rows[i] = seg / (KDIM / 4);
      cs[i] = seg % (KDIM / 4);
      int tk = tokens[min(node0 + rows[i], N_NODES - 1)];
      v[i] = *(const float4*)&Xv[(size_t)tk * KDIM + 4 * cs[i]];
    }
#pragma unroll
    for (int i = 0; i < NT; i++) {
      ushort4 h, l;
      h.x = f2bf(v[i].x); l.x = f2bf(v[i].x - bf2f(h.x));
      h.y = f2bf(v[i].y); l.y = f2bf(v[i].y - bf2f(h.y));
      h.z = f2bf(v[i].z); l.z = f2bf(v[i].z - bf2f(h.z));
      h.w = f2bf(v[i].w); l.w = f2bf(v[i].w - bf2f(h.w));
      *(ushort4*)&xh_lds[rows[i] * XS + 4 * cs[i]] = h;
      *(ushort4*)&xl_lds[rows[i] * XS + 4 * cs[i]] = l;
    }
  }
  __syncthreads();

  f32x16 acc;
#pragma unroll
  for (int r = 0; r < 16; r++) acc[r] = 0.f;

#pragma unroll
  for (int kh = 0; kh < KH; kh++) {
    const ushort_t* wb = Wsw + ((size_t)(wv * KH + kh) * 8) * 2 * 512 + lane * 8;
    bf16x8 wbh[8], wbl[8];
#pragma unroll
    for (int t = 0; t < 8; t++) {
      wbh[t] = *(const bf16x8*)(wb + (size_t)t * 1024);
      wbl[t] = *(const bf16x8*)(wb + (size_t)t * 1024 + 512);
    }
#pragma unroll
    for (int t = 0; t < 8; t++) {
      int ko = kh * 128 + t * 16 + fq * 8;
      bf16x8 ah = *(const bf16x8*)&xh_lds[fm * XS + ko];
      bf16x8 al = *(const bf16x8*)&xl_lds[fm * XS + ko];
      acc = __builtin_amdgcn_mfma_f32_32x32x16_bf16(ah, wbh[t], acc, 0, 0, 0);
      acc = __builtin_amdgcn_mfma_f32_32x32x16_bf16(ah, wbl[t], acc, 0, 0, 0);
      acc = __builtin_amdgcn_mfma_f32_32x32x16_bf16(al, wbh[t], acc, 0, 0, 0);
    }
  }
  int j = wv * 32 + fm;
  float bv = bias[j];
#pragma unroll
  for (int r = 0; r < 16; r++) {
    int row = (r & 3) + 8 * (r >> 2) + 4 * fq;
    int node = node0 + row;
    if (node < N_NODES)
      OutT[(size_t)node * D + j] = f2bf((acc[r] + bv) * dinvp[node]);
  }
}

// Edge-gather accumulate helper: unroll 8 outstanding row loads.
__device__ __forceinline__ void agg_edges(
    const unsigned int* __restrict__ tu, const int* __restrict__ csr,
    int e0, int e1, int lane, float& ax, float& ay) {
  for (int base = e0; base < e1; base += 64) {
    int cnt = min(64, e1 - base);
    int sidx = (lane < cnt) ? csr[base + lane] : 0;
    int i = 0;
    for (; i + 8 <= cnt; i += 8) {
      unsigned int u[8];
#pragma unroll
      for (int q = 0; q < 8; q++) {
        int s = __shfl(sidx, i + q);
        u[q] = tu[(size_t)s * 64 + lane];
      }
#pragma unroll
      for (int q = 0; q < 8; q++) {
        ax += bf2f((ushort_t)(u[q] & 0xFFFF));
        ay += bf2f((ushort_t)(u[q] >> 16));
      }
    }
    for (; i + 4 <= cnt; i += 4) {
      unsigned int u[4];
#pragma unroll
      for (int q = 0; q < 4; q++) {
        int s = __shfl(sidx, i + q);
        u[q] = tu[(size_t)s * 64 + lane];
      }
#pragma unroll
      for (int q = 0; q < 4; q++) {
        ax += bf2f((ushort_t)(u[q] & 0xFFFF));
        ay += bf2f((ushort_t)(u[q] >> 16));
      }
    }
    for (; i < cnt; i++) {
      int s = __shfl(sidx, i);
      unsigned int u = tu[(size_t)s * 64 + lane];
      ax += bf2f((ushort_t)(u & 0xFFFF));
      ay += bf2f((ushort_t)(u >> 16));
    }
  }
}

// ---------------- FUSED aggregate1 + conv2-GEMM ----------------
__global__ __launch_bounds__(256) void k_agg_gemm(
    const ushort_t* __restrict__ t1, const int* __restrict__ row_start,
    const int* __restrict__ csr, const float* __restrict__ dinv,
    const float* __restrict__ b1f,
    const ushort_t* __restrict__ Wsw, ushort_t* __restrict__ OutT2) {
  constexpr int XS = 136;
  __shared__ __align__(16) ushort_t xh_lds[32 * XS];
  __shared__ __align__(16) ushort_t xl_lds[32 * XS];

  int tid = threadIdx.x;
  int lane = tid & 63;
  int wv = tid >> 6;
  int node0 = blockIdx.x * 32;
  int fm = lane & 31;
  int fq = lane >> 5;

  const unsigned int* tu = (const unsigned int*)t1;
  float bx = b1f[2 * lane];
  float by = b1f[2 * lane + 1];

  for (int rr = 0; rr < 8; rr++) {
    int row = wv * 8 + rr;
    int node = node0 + row;
    float ax = 0.f, ay = 0.f;
    if (node < N_NODES) {
      unsigned int u = tu[(size_t)node * 64 + lane];  // self-loop (prescaled)
      ax = bf2f((ushort_t)(u & 0xFFFF));
      ay = bf2f((ushort_t)(u >> 16));
      agg_edges(tu, csr, row_start[node], row_start[node + 1], lane, ax, ay);
      float di = dinv[node];
      ax = fmaxf(di * ax + bx, 0.f);
      ay = fmaxf(di * ay + by, 0.f);
    }
    ushort2 h, l;
    h.x = f2bf(ax); l.x = f2bf(ax - bf2f(h.x));
    h.y = f2bf(ay); l.y = f2bf(ay - bf2f(h.y));
    *(ushort2*)&xh_lds[row * XS + 2 * lane] = h;
    *(ushort2*)&xl_lds[row * XS + 2 * lane] = l;
  }
  __syncthreads();

  f32x16 acc;
#pragma unroll
  for (int r = 0; r < 16; r++) acc[r] = 0.f;
  {
    const ushort_t* wb = Wsw + ((size_t)wv * 8) * 2 * 512 + lane * 8;
    bf16x8 wbh[8], wbl[8];
#pragma unroll
    for (int t = 0; t < 8; t++) {
      wbh[t] = *(const bf16x8*)(wb + (size_t)t * 1024);
      wbl[t] = *(const bf16x8*)(wb + (size_t)t * 1024 + 512);
    }
#pragma unroll
    for (int t = 0; t < 8; t++) {
      int ko = t * 16 + fq * 8;
      bf16x8 ah = *(const bf16x8*)&xh_lds[fm * XS + ko];
      bf16x8 al = *(const bf16x8*)&xl_lds[fm * XS + ko];
      acc = __builtin_amdgcn_mfma_f32_32x32x16_bf16(ah, wbh[t], acc, 0, 0, 0);
      acc = __builtin_amdgcn_mfma_f32_32x32x16_bf16(ah, wbl[t], acc, 0, 0, 0);
      acc = __builtin_amdgcn_mfma_f32_32x32x16_bf16(al, wbh[t], acc, 0, 0, 0);
    }
  }
  int j = wv * 32 + fm;
#pragma unroll
  for (int r = 0; r < 16; r++) {
    int row = (r & 3) + 8 * (r >> 2) + 4 * fq;
    int node = node0 + row;
    if (node < N_NODES)
      OutT2[(size_t)node * D + j] = f2bf(acc[r] * dinv[node]);
  }
}

// ---------------- final aggregation -> fp32 out ----------------
__global__ __launch_bounds__(256) void k_aggregate_out(
    const ushort_t* __restrict__ t, const int* __restrict__ row_start,
    const int* __restrict__ csr, const float* __restrict__ dinv,
    const float* __restrict__ bias, float* __restrict__ out_f) {
  int wave = threadIdx.x >> 6;
  int lane = threadIdx.x & 63;
  int node = blockIdx.x * 4 + wave;
  if (node >= N_NODES) return;
  const unsigned int* tu = (const unsigned int*)t;
  float ax, ay;
  {
    unsigned int u = tu[(size_t)node * 64 + lane];
    ax = bf2f((ushort_t)(u & 0xFFFF));
    ay = bf2f((ushort_t)(u >> 16));
  }
  agg_edges(tu, csr, row_start[node], row_start[node + 1], lane, ax, ay);
  float di = dinv[node];
  ax = di * ax + bias[2 * lane];
  ay = di * ay + bias[2 * lane + 1];
  float2 o; o.x = ax; o.y = ay;
  *(float2*)&out_f[(size_t)node * D + 2 * lane] = o;
}

extern "C" void kernel_launch(void* const* d_in, const int* in_sizes, int n_in,
                              void* d_out, int out_size, void* d_ws, size_t ws_size,
                              hipStream_t stream) {
  const int* tokens = (const int*)d_in[0];
  const int* edge = (const int*)d_in[1];  // [2][E]
  const float* embed = (const float*)d_in[2];
  const float* Wn = (const float*)d_in[3];
  const float* bn = (const float*)d_in[4];
  const float* w1 = (const float*)d_in[5];
  const float* b1 = (const float*)d_in[6];
  const float* w2 = (const float*)d_in[7];
  const float* b2 = (const float*)d_in[8];
  float* out = (float*)d_out;  // fp32 output

  const int* src = edge;
  const int* dst = edge + N_EDGES;

  char* ws = (char*)d_ws;
  ushort_t* T1 = (ushort_t*)ws;                    // 12,800,000 B
  ushort_t* T2 = (ushort_t*)(ws + 12800000);       // 12,800,000 B
  float* dinv = (float*)(ws + 38400000);           // 200,000 B
  int* row_start = (int*)(ws + 38600064);          // 200,004 B (pad)
  int* degcur = (int*)(ws + 38800128);             // 400,000 B (deg | cursor)
  int* csr = (int*)(ws + 39200128);                // 2,400,000 B
  int* partial = (int*)(ws + 41600192);            // 196 B
  ushort_t* WcSw = (ushort_t*)(ws + 41600512);     // 131,072 B (swizzled hi/lo)
  ushort_t* W2Sw = (ushort_t*)(ws + 41731584);     // 65,536 B (swizzled hi/lo)
  float* bias_ws = (float*)(ws + 41797120);        // bc | b1 | b2 (1,536 B)
  float* bcf = bias_ws;
  float* b1f = bias_ws + 128;
  float* b2f = bias_ws + 256;
  int* deg = degcur;
  int* cursor = degcur + N_NODES;

  // --- zero deg (cursor zeroed in scan_final); prep + degree count ---
  hipMemsetAsync(deg, 0, N_NODES * sizeof(int), stream);
  k_prep_deg<<<193 + EDGE_BLOCKS, 256, 0, stream>>>(
      Wn, w1, bn, w2, b1, b2, dst, WcSw, bcf, W2Sw, b1f, b2f, deg);

  // --- CSR scan ---
  k_partial<<<N_CHUNKS, 256, 0, stream>>>(deg, partial);
  k_scan_final<<<N_CHUNKS, 256, 0, stream>>>(deg, partial, row_start, dinv, cursor);

  // --- merged: conv1 T1 = (gather(e)@Wc^T + bc)*dinv  ||  CSR fill ---
  k_gemm_fill<<<GEMM_BLOCKS + EDGE_BLOCKS, 256, 0, stream>>>(
      embed, tokens, WcSw, bcf, dinv, T1, src, dst, row_start, cursor, csr);

  // --- fused: x1 = relu(agg(T1)+b1); T2 = (x1 @ w2^T)*dinv ---
  k_agg_gemm<<<GEMM_BLOCKS, 256, 0, stream>>>(
      T1, row_start, csr, dinv, b1f, W2Sw, T2);

  // --- final aggregate + b2 -> out (fp32) ---
  k_aggregate_out<<<(N_NODES + 3) / 4, 256, 0, stream>>>(
      T2, row_start, csr, dinv, b2f, out);
}